// Round 7
// baseline (85199.115 us; speedup 1.0000x reference)
//
#include <hip/hip_runtime.h>
#include <hip/hip_bf16.h>

// ---------------------------------------------------------------------------
// STD2Vformer forward, MI355X. Round 7: f32-OUTPUT oracle.
// Theory: reference output dtype is f32 (probe-invisibility proof, R6).
// Same audited naive pipeline as R5/R6; final store is float. All kernels
// renamed *_r7 so a stale-binary reuse is detectable (it would reproduce
// 4.235840e-02 exactly; a fresh binary cannot).
// ---------------------------------------------------------------------------

#define NN 883
#define BB 32
#define NL 10596            // N*L
#define CNT_PER_C 339072.0f // B*N*L
#define TOT_X 1017216       // B*C*N*L
#define AMAT_N 779689       // N*N

static __device__ __forceinline__ float bf2f(__hip_bfloat16 v) { return __bfloat162float(v); }
static __device__ __forceinline__ float ldf(const void* p, int i, int f) {
    return f ? ((const float*)p)[i] : bf2f(((const __hip_bfloat16*)p)[i]);
}

// ---------------- sentinel: d_out = 1000.0f ----------------
__global__ void k_sent_r7(float* __restrict__ out, int n)
{
    int i = blockIdx.x*256 + threadIdx.x;
    if (i < n) out[i] = 1000.0f;
}

// ---------------- input dtype probe ----------------
__global__ void k_probe_r7(const unsigned short* __restrict__ u, int* __restrict__ flag)
{
    int t = threadIdx.x, cnt = 0;
    for (int i = t; i < 4096; i += 256) {
        int e = (u[i] >> 7) & 0xFF;
        cnt += (e >= 0xC0);
    }
    __shared__ int r[256];
    r[t] = cnt; __syncthreads();
    for (int s = 128; s > 0; s >>= 1) { if (t < s) r[t] += r[t+s]; __syncthreads(); }
    if (t == 0) *flag = (r[0] > 8) ? 1 : 0;
}

// ---------------- prep: tidx, didx, phi(B,24) ----------------
__global__ void k_prep_r7(const void* __restrict__ seqs, const void* __restrict__ tgts,
                          const void* __restrict__ w0, const void* __restrict__ b0,
                          const void* __restrict__ d2vW, const void* __restrict__ d2vb,
                          const int* __restrict__ dflag,
                          int* __restrict__ tidx, int* __restrict__ didx,
                          float* __restrict__ phi)
{
    int f = *dflag, t = threadIdx.x;
    if (t < 32) {
        int b = t;
        float h  = (ldf(seqs, (b*5+3)*12 + 11, f) + 0.5f) * 23.0f;
        float mi = (ldf(seqs, (b*5+4)*12 + 11, f) + 0.5f) * 59.0f;
        int ti = (int)((h * 60.0f + mi) / 5.0f);
        tidx[b] = ti < 0 ? 0 : (ti > 287 ? 287 : ti);
        int di = (int)((ldf(seqs, (b*5+2)*12 + 11, f) + 0.5f) * 6.0f);
        didx[b] = di < 0 ? 0 : (di > 6 ? 6 : di);
    }
    for (int i = t; i < 768; i += 256) {
        int b = i / 24, tt = i % 24;
        float tau[5];
        #pragma unroll
        for (int d = 0; d < 5; d++)
            tau[d] = (tt < 12) ? ldf(seqs, (b*5+d)*12 + tt, f)
                               : ldf(tgts, (b*5+d)*12 + tt - 12, f);
        float s = ldf(b0, 0, f);
        #pragma unroll
        for (int d = 0; d < 5; d++) s += tau[d] * ldf(w0, d, f);
        for (int k = 0; k < 16; k++) {
            float arg = ldf(d2vb, k, f);
            #pragma unroll
            for (int d = 0; d < 5; d++) arg += tau[d] * ldf(d2vW, k*5 + d, f);
            s += sinf(arg);
        }
        phi[i] = s;
    }
}

// ---------------- e1 = mb@We1, e2 = mb@We2 ----------------
__global__ void k_e_r7(const void* __restrict__ mb, const void* __restrict__ We1,
                       const void* __restrict__ We2, const int* __restrict__ dflag,
                       float* __restrict__ e1, float* __restrict__ e2)
{
    int f = *dflag;
    int idx = blockIdx.x*256 + threadIdx.x;       // 2*113024 exactly
    int which = idx >= 113024;
    int j = which ? idx - 113024 : idx;
    int d = j & 127, n = j >> 7;
    const void* W = which ? We2 : We1;
    float s = 0.f;
    for (int k = 0; k < 128; k++)
        s += ldf(mb, n*128 + k, f) * ldf(W, k*128 + d, f);
    (which ? e2 : e1)[j] = s;
}

// ---------------- a[n,m] = e1[n]·e2[m] ----------------
__global__ void k_amat_r7(const float* __restrict__ e1, const float* __restrict__ e2,
                          float* __restrict__ amat)
{
    int i = blockIdx.x*256 + threadIdx.x;
    if (i >= AMAT_N) return;
    int n = i / NN, m = i % NN;
    float s = 0.f;
    for (int k = 0; k < 128; k++) s += e1[n*128 + k] * e2[m*128 + k];
    amat[i] = s;
}

// ---- per-row: standardize(ddof=1, two-pass), relu, diag-mask, softmax in place ----
__global__ void k_rowsm_r7(float* __restrict__ amat)
{
    int n = blockIdx.x, t = threadIdx.x;
    __shared__ float arow[NN];
    __shared__ float red[256];
    for (int m = t; m < NN; m += 256) arow[m] = amat[n*NN + m];
    __syncthreads();
    float s = 0.f;
    for (int m = t; m < NN; m += 256) s += arow[m];
    red[t] = s; __syncthreads();
    for (int st = 128; st > 0; st >>= 1) { if (t < st) red[t] += red[t+st]; __syncthreads(); }
    float mean = red[0] / 883.0f; __syncthreads();
    float ss = 0.f;
    for (int m = t; m < NN; m += 256) { float d = arow[m] - mean; ss += d*d; }
    red[t] = ss; __syncthreads();
    for (int st = 128; st > 0; st >>= 1) { if (t < st) red[t] += red[t+st]; __syncthreads(); }
    float rstd = 1.0f / sqrtf(red[0] / 882.0f); __syncthreads();
    for (int m = t; m < NN; m += 256) {
        float z = (arow[m] - mean) * rstd;
        z = fmaxf(z, 0.f);
        if (m == n) z -= 1e6f;
        arow[m] = z;
    }
    __syncthreads();
    float mx = -3.4e38f;
    for (int m = t; m < NN; m += 256) mx = fmaxf(mx, arow[m]);
    red[t] = mx; __syncthreads();
    for (int st = 128; st > 0; st >>= 1) { if (t < st) red[t] = fmaxf(red[t], red[t+st]); __syncthreads(); }
    float M = red[0]; __syncthreads();
    float ds = 0.f;
    for (int m = t; m < NN; m += 256) { float e = expf(arow[m] - M); arow[m] = e; ds += e; }
    red[t] = ds; __syncthreads();
    for (int st = 128; st > 0; st >>= 1) { if (t < st) red[t] += red[t+st]; __syncthreads(); }
    float inv = 1.0f / red[0]; __syncthreads();
    for (int m = t; m < NN; m += 256) amat[n*NN + m] = arow[m] * inv;
}

// ---------------- top-9 per row ----------------
__global__ void k_top9_r7(const float* __restrict__ amat,
                          float* __restrict__ topval, int* __restrict__ topidx)
{
    int n = blockIdx.x, t = threadIdx.x;
    __shared__ float arow[NN];
    __shared__ float red[256];
    __shared__ int redi[256];
    for (int m = t; m < NN; m += 256) arow[m] = amat[n*NN + m];
    __syncthreads();
    for (int j = 0; j < 9; j++) {
        float bv = -1.f; int bi = 0;
        for (int m = t; m < NN; m += 256) { float v = arow[m]; if (v > bv) { bv = v; bi = m; } }
        red[t] = bv; redi[t] = bi; __syncthreads();
        for (int st = 128; st > 0; st >>= 1) {
            if (t < st) {
                float ov = red[t+st]; int oi = redi[t+st];
                if (ov > red[t] || (ov == red[t] && oi < redi[t])) { red[t] = ov; redi[t] = oi; }
            }
            __syncthreads();
        }
        if (t == 0) {
            topval[n*9 + j] = red[0];
            topidx[n*9 + j] = redi[0];
            arow[redi[0]] = -1.f;
        }
        __syncthreads();
    }
}

// ---------------- bn1 stats over input (B,C,N,L) ----------------
__global__ void k_bn1_r7(const void* __restrict__ x, const int* __restrict__ dflag,
                         float* __restrict__ st)
{
    int f = *dflag;
    float s[3] = {0,0,0}, q[3] = {0,0,0};
    for (int i = blockIdx.x*256 + threadIdx.x; i < TOT_X; i += 512*256) {
        int c = (i / NL) % 3;
        float v = ldf(x, i, f);
        s[c] += v; q[c] += v*v;
    }
    __shared__ float red[6][256];
    int t = threadIdx.x;
    #pragma unroll
    for (int j = 0; j < 3; j++) { red[j][t] = s[j]; red[3+j][t] = q[j]; }
    __syncthreads();
    for (int st_ = 128; st_ > 0; st_ >>= 1) {
        if (t < st_) {
            #pragma unroll
            for (int j = 0; j < 6; j++) red[j][t] += red[j][t+st_];
        }
        __syncthreads();
    }
    if (t < 6) atomicAdd(&st[t], red[t][0]);
}

// ---------------- xb = bn1(input) ----------------
__global__ void k_xb_r7(const void* __restrict__ in, const int* __restrict__ dflag,
                        const float* __restrict__ st, float* __restrict__ xb)
{
    int f = *dflag;
    int i = blockIdx.x*256 + threadIdx.x;
    if (i >= TOT_X) return;
    int c = (i / NL) % 3;
    float m = st[c] * (1.0f/CNT_PER_C);
    float v = st[3+c] * (1.0f/CNT_PER_C) - m*m;
    xb[i] = (ldf(in, i, f) - m) / sqrtf(v + 1e-5f);
}

// ---------------- naive encoder per (b,n): hidden -> 3 layers -> reg ----------------
__global__ void __launch_bounds__(256)
k_enc_r7(const float* __restrict__ xb, const void* __restrict__ mb,
         const void* __restrict__ tide, const void* __restrict__ diwe,
         const void* __restrict__ tsW, const void* __restrict__ tsb,
         const void* __restrict__ W1, const void* __restrict__ B1,
         const void* __restrict__ W2, const void* __restrict__ B2,
         const void* __restrict__ regW, const void* __restrict__ regB,
         const int* __restrict__ tidx, const int* __restrict__ didx,
         const int* __restrict__ dflag, float* __restrict__ regb)
{
    int f = *dflag;
    int n = blockIdx.x, b = blockIdx.y, t = threadIdx.x;
    __shared__ float h[512], hn[512], xbs[36];
    if (t < 36) {
        int c = t / 12, l = t % 12;
        xbs[t] = xb[((b*3 + c)*NN + n)*12 + l];
    }
    __syncthreads();
    #pragma unroll
    for (int half = 0; half < 2; half++) {
        int ch = t + half*256;
        float v;
        if (ch < 128) {
            float acc = ldf(tsb, ch, f);
            for (int k = 0; k < 36; k++) acc += xbs[k] * ldf(tsW, ch*36 + k, f);
            v = acc;
        } else if (ch < 256) v = ldf(mb, n*128 + ch - 128, f);
        else if (ch < 384) v = ldf(tide, tidx[b]*128 + ch - 256, f);
        else v = ldf(diwe, didx[b]*128 + ch - 384, f);
        h[ch] = v;
    }
    __syncthreads();
    for (int i = 0; i < 3; i++) {
        #pragma unroll
        for (int half = 0; half < 2; half++) {
            int ho = t + half*256;
            float acc = ldf(B1, i*512 + ho, f);
            int base = (i*512 + ho)*512;
            for (int k = 0; k < 512; k++) acc += ldf(W1, base + k, f) * h[k];
            hn[ho] = fmaxf(acc, 0.f);
        }
        __syncthreads();
        float upd[2];
        #pragma unroll
        for (int half = 0; half < 2; half++) {
            int ho = t + half*256;
            float acc = ldf(B2, i*512 + ho, f);
            int base = (i*512 + ho)*512;
            for (int k = 0; k < 512; k++) acc += ldf(W2, base + k, f) * hn[k];
            upd[half] = acc;
        }
        __syncthreads();
        #pragma unroll
        for (int half = 0; half < 2; half++) { int ho = t + half*256; h[ho] += upd[half]; }
        __syncthreads();
    }
    if (t < 36) {
        float acc = ldf(regB, t, f);
        for (int k = 0; k < 512; k++) acc += ldf(regW, t*512 + k, f) * h[k];
        regb[((size_t)b*36 + t)*NN + n] = acc;
    }
}

// ---------------- bn2 stats over reg (B,36,N) ----------------
__global__ void k_bn2_r7(const float* __restrict__ x, float* __restrict__ st)
{
    float s[3] = {0,0,0}, q[3] = {0,0,0};
    for (int i = blockIdx.x*256 + threadIdx.x; i < TOT_X; i += 512*256) {
        int c = ((i / NN) % 36) / 12;
        float v = x[i];
        s[c] += v; q[c] += v*v;
    }
    __shared__ float red[6][256];
    int t = threadIdx.x;
    #pragma unroll
    for (int j = 0; j < 3; j++) { red[j][t] = s[j]; red[3+j][t] = q[j]; }
    __syncthreads();
    for (int st_ = 128; st_ > 0; st_ >>= 1) {
        if (t < st_) {
            #pragma unroll
            for (int j = 0; j < 6; j++) red[j][t] += red[j][t+st_];
        }
        __syncthreads();
    }
    if (t < 6) atomicAdd(&st[t], red[t][0]);
}

// ---------------- xpre = bn2(hid) + conv(xb); bn3 stats ----------------
__global__ void k_xpre_r7(const float* __restrict__ regb, const float* __restrict__ xb,
                          const void* __restrict__ convW, const void* __restrict__ convb,
                          const int* __restrict__ dflag,
                          const float* __restrict__ st2, float* __restrict__ st3,
                          float* __restrict__ xpre)
{
    int f = *dflag;
    int i = blockIdx.x*256 + threadIdx.x;
    float s[3] = {0,0,0}, q[3] = {0,0,0};
    if (i < TOT_X) {
        int b = i / 31788, r1 = i % 31788;
        int c = r1 / NL, r2 = r1 % NL;
        int n = r2 / 12, l = r2 % 12;
        float m2 = st2[c] * (1.0f/CNT_PER_C);
        float v2 = st2[3+c] * (1.0f/CNT_PER_C) - m2*m2;
        float hidv = (regb[((size_t)b*36 + c*12 + l)*NN + n] - m2) / sqrtf(v2 + 1e-5f);
        float cx = ldf(convb, c, f);
        #pragma unroll
        for (int cc = 0; cc < 3; cc++)
            cx += ldf(convW, c*3 + cc, f) * xb[((b*3 + cc)*NN + n)*12 + l];
        float v = hidv + cx;
        xpre[i] = v;
        s[c] = v; q[c] = v*v;
    }
    __shared__ float red[6][256];
    int t = threadIdx.x;
    #pragma unroll
    for (int j = 0; j < 3; j++) { red[j][t] = s[j]; red[3+j][t] = q[j]; }
    __syncthreads();
    for (int st_ = 128; st_ > 0; st_ >>= 1) {
        if (t < st_) {
            #pragma unroll
            for (int j = 0; j < 6; j++) red[j][t] += red[j][t+st_];
        }
        __syncthreads();
    }
    if (t < 6) atomicAdd(&st3[t], red[t][0]);
}

// ---------------- naive tail per (b,n): full fus/glu; f32 OUTPUT ----------------
__global__ void __launch_bounds__(64)
k_tail_r7(const float* __restrict__ xpre, const float* __restrict__ st3,
          const float* __restrict__ phi, const float* __restrict__ topval,
          const int* __restrict__ topidx,
          const void* __restrict__ wie, const void* __restrict__ mixp,
          const void* __restrict__ fusW, const void* __restrict__ fusb,
          const void* __restrict__ g1W, const void* __restrict__ g1b,
          const void* __restrict__ g2W, const void* __restrict__ g2b,
          const int* __restrict__ dflag, float* __restrict__ out)
{
    int f = *dflag;
    int n = blockIdx.x, b = blockIdx.y, t = threadIdx.x;
    __shared__ float xe[3][10][12], mn[3][10], phis[24], ws[10];
    __shared__ float pm[3][10][12], pred[3][12], pred2[128][12];
    float m3[3], rs3[3];
    #pragma unroll
    for (int c = 0; c < 3; c++) {
        float m = st3[c] * (1.0f/CNT_PER_C);
        float v = st3[3+c] * (1.0f/CNT_PER_C) - m*m;
        m3[c] = m; rs3[c] = 1.0f / sqrtf(v + 1e-5f);
    }
    if (t < 24) phis[t] = phi[b*24 + t];
    if (t < 10) ws[t] = (t == 0 ? 1.0f : topval[n*9 + t - 1]) * ldf(wie, t, f);
    for (int i = t; i < 360; i += 64) {
        int c = i / 120, m = (i / 12) % 10, l = i % 12;
        int nn2 = (m == 0) ? n : topidx[n*9 + m - 1];
        xe[c][m][l] = (xpre[((size_t)(b*3 + c)*NN + nn2)*12 + l] - m3[c]) * rs3[c];
    }
    __syncthreads();
    if (t < 30) {
        int c = t / 10, m = t % 10;
        float s = 0.f;
        #pragma unroll
        for (int l = 0; l < 12; l++) s += xe[c][m][l];
        mn[c][m] = s * (1.0f/12.0f);
    }
    __syncthreads();
    float mix = ldf(mixp, 0, f);
    for (int pr = t; pr < 120; pr += 64) {
        int m = pr / 12, p = pr % 12;
        float y[3], sc[12], mx = -3.4e38f;
        #pragma unroll
        for (int c = 0; c < 3; c++) y[c] = phis[12+p] + mix*mn[c][m];
        #pragma unroll
        for (int l = 0; l < 12; l++) {
            float v = 0.f;
            #pragma unroll
            for (int c = 0; c < 3; c++) v += y[c] * (phis[l] + mix*mn[c][m]);
            sc[l] = v * (1.0f/36.0f); mx = fmaxf(mx, sc[l]);
        }
        float den = 0.f;
        #pragma unroll
        for (int l = 0; l < 12; l++) { float e = expf(sc[l] - mx); sc[l] = e; den += e; }
        float inv = 1.0f/den;
        float p0 = 0.f, p1 = 0.f, p2 = 0.f;
        #pragma unroll
        for (int l = 0; l < 12; l++) {
            float a = sc[l]*inv;
            p0 += a*xe[0][m][l]; p1 += a*xe[1][m][l]; p2 += a*xe[2][m][l];
        }
        pm[0][m][p] = p0; pm[1][m][p] = p1; pm[2][m][p] = p2;
    }
    __syncthreads();
    if (t < 36) {
        int c = t/12, p = t%12;
        float s = 0.f;
        #pragma unroll
        for (int m = 0; m < 10; m++) s += pm[c][m][p]*ws[m];
        pred[c][p] = s;
    }
    __syncthreads();
    for (int i = t; i < 1536; i += 64) {
        int d = i / 12, p = i % 12;
        float s = ldf(fusb, d, f);
        #pragma unroll
        for (int c = 0; c < 3; c++) s += pred[c][p] * ldf(fusW, c*128 + d, f);
        pred2[d][p] = s;
    }
    __syncthreads();
    if (t < 36) {
        int o = t/12, p = t%12;
        float o1 = ldf(g1b, o, f), o2 = ldf(g2b, o, f);
        for (int d = 0; d < 128; d++) {
            o1 += pred2[d][p] * ldf(g1W, d*3 + o, f);
            o2 += pred2[d][p] * ldf(g2W, d*3 + o, f);
        }
        out[((size_t)(b*3 + o)*NN + n)*12 + p] = o1 / (1.0f + expf(-o2));
    }
}

// ---------------------------------------------------------------------------
extern "C" void kernel_launch(void* const* d_in, const int* in_sizes, int n_in,
                              void* d_out, int out_size, void* d_ws, size_t ws_size,
                              hipStream_t stream)
{
    (void)in_sizes; (void)n_in;
    char* w = (char*)d_ws;
    auto alloc = [&](size_t bytes) { char* p = w; w += (bytes + 255) & ~(size_t)255; return p; };

    float* e1     = (float*)alloc(113024*4);
    float* e2     = (float*)alloc(113024*4);
    float* amat   = (float*)alloc((size_t)AMAT_N*4);
    float* xb     = (float*)alloc((size_t)TOT_X*4);
    float* regb   = (float*)alloc((size_t)TOT_X*4);
    float* xpre   = (float*)alloc((size_t)TOT_X*4);
    float* phi    = (float*)alloc(768*4);
    float* topval = (float*)alloc(7947*4);
    int*   topidx = (int*)alloc(7947*4);
    int*   tidx   = (int*)alloc(32*4);
    int*   didx   = (int*)alloc(32*4);
    float* stats  = (float*)alloc(18*4);  // bn1|bn2|bn3
    int*   dflag  = (int*)alloc(4);
    size_t needed = (size_t)(w - (char*)d_ws);

    if (ws_size < needed) {   // loud sentinel: absmax ~1000 reports "ws too small"
        k_sent_r7<<<(out_size + 255)/256, 256, 0, stream>>>((float*)d_out, out_size);
        return;
    }

    hipMemsetAsync(stats, 0, 18*4, stream);

    k_probe_r7<<<1, 256, 0, stream>>>((const unsigned short*)d_in[0], dflag);
    k_prep_r7<<<1, 256, 0, stream>>>(d_in[2], d_in[3], d_in[19], d_in[20], d_in[21], d_in[22],
                                     dflag, tidx, didx, phi);
    k_e_r7<<<883, 256, 0, stream>>>(d_in[4], d_in[5], d_in[6], dflag, e1, e2);
    k_amat_r7<<<3047, 256, 0, stream>>>(e1, e2, amat);
    k_rowsm_r7<<<883, 256, 0, stream>>>(amat);
    k_top9_r7<<<883, 256, 0, stream>>>(amat, topval, topidx);
    k_bn1_r7<<<512, 256, 0, stream>>>(d_in[0], dflag, stats);
    k_xb_r7<<<3974, 256, 0, stream>>>(d_in[0], dflag, stats, xb);
    k_enc_r7<<<dim3(NN, BB), 256, 0, stream>>>(xb, d_in[4], d_in[7], d_in[8], d_in[9], d_in[10],
                                               d_in[13], d_in[14], d_in[15], d_in[16],
                                               d_in[17], d_in[18], tidx, didx, dflag, regb);
    k_bn2_r7<<<512, 256, 0, stream>>>(regb, stats + 6);
    k_xpre_r7<<<3974, 256, 0, stream>>>(regb, xb, d_in[11], d_in[12], dflag,
                                        stats + 6, stats + 12, xpre);
    k_tail_r7<<<dim3(NN, BB), 64, 0, stream>>>(xpre, stats + 12, phi, topval, topidx,
                                               d_in[24], d_in[23], d_in[25], d_in[26],
                                               d_in[27], d_in[28], d_in[29], d_in[30],
                                               dflag, (float*)d_out);
}

// Round 8
// 1788.932 us; speedup vs baseline: 47.6257x; 47.6257x over previous
//
#include <hip/hip_runtime.h>
#include <hip/hip_bf16.h>

// ---------------------------------------------------------------------------
// STD2Vformer forward, MI355X. Round 8: R7 (PASSED, 85 ms) + MFMA encoder.
// Encoder GEMMs: 128x128 tile, bf16 hi/lo error-compensated (3 MFMAs/frag,
// ~f32 precision). Activations f32 n-major in ws; residual f32 in-place.
// Self-check after first gemm gates the (slow) R7 VALU encoder as fallback.
// ---------------------------------------------------------------------------

#define NN 883
#define NPAD 896
#define BB 32
#define HH 512
#define NL 10596            // N*L
#define CNT_PER_C 339072.0f // B*N*L
#define TOT_X 1017216       // B*C*N*L
#define AMAT_N 779689       // N*N

typedef __attribute__((ext_vector_type(8))) short bf16x8;
typedef __attribute__((ext_vector_type(4))) float f32x4;

static __device__ __forceinline__ float bf2f(__hip_bfloat16 v) { return __bfloat162float(v); }
static __device__ __forceinline__ float ldf(const void* p, long i, int f) {
    return f ? ((const float*)p)[i] : bf2f(((const __hip_bfloat16*)p)[i]);
}
static __device__ __forceinline__ short bfbits(float v) {
    __hip_bfloat16 h = __float2bfloat16(v);
    return *(short*)&h;
}

// ---------------- sentinel ----------------
__global__ void k_sent_r8(float* __restrict__ out, int n)
{
    int i = blockIdx.x*256 + threadIdx.x;
    if (i < n) out[i] = 1000.0f;
}

// ---------------- input dtype probe ----------------
__global__ void k_probe_r8(const unsigned short* __restrict__ u, int* __restrict__ flag)
{
    int t = threadIdx.x, cnt = 0;
    for (int i = t; i < 4096; i += 256) {
        int e = (u[i] >> 7) & 0xFF;
        cnt += (e >= 0xC0);
    }
    __shared__ int r[256];
    r[t] = cnt; __syncthreads();
    for (int s = 128; s > 0; s >>= 1) { if (t < s) r[t] += r[t+s]; __syncthreads(); }
    if (t == 0) *flag = (r[0] > 8) ? 1 : 0;
}

// ---------------- prep: tidx, didx, phi(B,24) ----------------
__global__ void k_prep_r8(const void* __restrict__ seqs, const void* __restrict__ tgts,
                          const void* __restrict__ w0, const void* __restrict__ b0,
                          const void* __restrict__ d2vW, const void* __restrict__ d2vb,
                          const int* __restrict__ dflag,
                          int* __restrict__ tidx, int* __restrict__ didx,
                          float* __restrict__ phi)
{
    int f = *dflag, t = threadIdx.x;
    if (t < 32) {
        int b = t;
        float h  = (ldf(seqs, (b*5+3)*12 + 11, f) + 0.5f) * 23.0f;
        float mi = (ldf(seqs, (b*5+4)*12 + 11, f) + 0.5f) * 59.0f;
        int ti = (int)((h * 60.0f + mi) / 5.0f);
        tidx[b] = ti < 0 ? 0 : (ti > 287 ? 287 : ti);
        int di = (int)((ldf(seqs, (b*5+2)*12 + 11, f) + 0.5f) * 6.0f);
        didx[b] = di < 0 ? 0 : (di > 6 ? 6 : di);
    }
    for (int i = t; i < 768; i += 256) {
        int b = i / 24, tt = i % 24;
        float tau[5];
        #pragma unroll
        for (int d = 0; d < 5; d++)
            tau[d] = (tt < 12) ? ldf(seqs, (b*5+d)*12 + tt, f)
                               : ldf(tgts, (b*5+d)*12 + tt - 12, f);
        float s = ldf(b0, 0, f);
        #pragma unroll
        for (int d = 0; d < 5; d++) s += tau[d] * ldf(w0, d, f);
        for (int k = 0; k < 16; k++) {
            float arg = ldf(d2vb, k, f);
            #pragma unroll
            for (int d = 0; d < 5; d++) arg += tau[d] * ldf(d2vW, k*5 + d, f);
            s += sinf(arg);
        }
        phi[i] = s;
    }
}

// ---------------- e1 = mb@We1, e2 = mb@We2 ----------------
__global__ void k_e_r8(const void* __restrict__ mb, const void* __restrict__ We1,
                       const void* __restrict__ We2, const int* __restrict__ dflag,
                       float* __restrict__ e1, float* __restrict__ e2)
{
    int f = *dflag;
    int idx = blockIdx.x*256 + threadIdx.x;
    int which = idx >= 113024;
    int j = which ? idx - 113024 : idx;
    int d = j & 127, n = j >> 7;
    const void* W = which ? We2 : We1;
    float s = 0.f;
    for (int k = 0; k < 128; k++)
        s += ldf(mb, n*128 + k, f) * ldf(W, k*128 + d, f);
    (which ? e2 : e1)[j] = s;
}

// ---------------- a[n,m] = e1[n]·e2[m] ----------------
__global__ void k_amat_r8(const float* __restrict__ e1, const float* __restrict__ e2,
                          float* __restrict__ amat)
{
    int i = blockIdx.x*256 + threadIdx.x;
    if (i >= AMAT_N) return;
    int n = i / NN, m = i % NN;
    float s = 0.f;
    for (int k = 0; k < 128; k++) s += e1[n*128 + k] * e2[m*128 + k];
    amat[i] = s;
}

// ---- per-row: standardize(ddof=1), relu, diag-mask, softmax in place ----
__global__ void k_rowsm_r8(float* __restrict__ amat)
{
    int n = blockIdx.x, t = threadIdx.x;
    __shared__ float arow[NN];
    __shared__ float red[256];
    for (int m = t; m < NN; m += 256) arow[m] = amat[n*NN + m];
    __syncthreads();
    float s = 0.f;
    for (int m = t; m < NN; m += 256) s += arow[m];
    red[t] = s; __syncthreads();
    for (int st = 128; st > 0; st >>= 1) { if (t < st) red[t] += red[t+st]; __syncthreads(); }
    float mean = red[0] / 883.0f; __syncthreads();
    float ss = 0.f;
    for (int m = t; m < NN; m += 256) { float d = arow[m] - mean; ss += d*d; }
    red[t] = ss; __syncthreads();
    for (int st = 128; st > 0; st >>= 1) { if (t < st) red[t] += red[t+st]; __syncthreads(); }
    float rstd = 1.0f / sqrtf(red[0] / 882.0f); __syncthreads();
    for (int m = t; m < NN; m += 256) {
        float z = (arow[m] - mean) * rstd;
        z = fmaxf(z, 0.f);
        if (m == n) z -= 1e6f;
        arow[m] = z;
    }
    __syncthreads();
    float mx = -3.4e38f;
    for (int m = t; m < NN; m += 256) mx = fmaxf(mx, arow[m]);
    red[t] = mx; __syncthreads();
    for (int st = 128; st > 0; st >>= 1) { if (t < st) red[t] = fmaxf(red[t], red[t+st]); __syncthreads(); }
    float M = red[0]; __syncthreads();
    float ds = 0.f;
    for (int m = t; m < NN; m += 256) { float e = expf(arow[m] - M); arow[m] = e; ds += e; }
    red[t] = ds; __syncthreads();
    for (int st = 128; st > 0; st >>= 1) { if (t < st) red[t] += red[t+st]; __syncthreads(); }
    float inv = 1.0f / red[0]; __syncthreads();
    for (int m = t; m < NN; m += 256) amat[n*NN + m] = arow[m] * inv;
}

// ---------------- top-9 per row ----------------
__global__ void k_top9_r8(const float* __restrict__ amat,
                          float* __restrict__ topval, int* __restrict__ topidx)
{
    int n = blockIdx.x, t = threadIdx.x;
    __shared__ float arow[NN];
    __shared__ float red[256];
    __shared__ int redi[256];
    for (int m = t; m < NN; m += 256) arow[m] = amat[n*NN + m];
    __syncthreads();
    for (int j = 0; j < 9; j++) {
        float bv = -1.f; int bi = 0;
        for (int m = t; m < NN; m += 256) { float v = arow[m]; if (v > bv) { bv = v; bi = m; } }
        red[t] = bv; redi[t] = bi; __syncthreads();
        for (int st = 128; st > 0; st >>= 1) {
            if (t < st) {
                float ov = red[t+st]; int oi = redi[t+st];
                if (ov > red[t] || (ov == red[t] && oi < redi[t])) { red[t] = ov; redi[t] = oi; }
            }
            __syncthreads();
        }
        if (t == 0) {
            topval[n*9 + j] = red[0];
            topidx[n*9 + j] = redi[0];
            arow[redi[0]] = -1.f;
        }
        __syncthreads();
    }
}

// ---------------- bn1 stats ----------------
__global__ void k_bn1_r8(const void* __restrict__ x, const int* __restrict__ dflag,
                         float* __restrict__ st)
{
    int f = *dflag;
    float s[3] = {0,0,0}, q[3] = {0,0,0};
    for (int i = blockIdx.x*256 + threadIdx.x; i < TOT_X; i += 512*256) {
        int c = (i / NL) % 3;
        float v = ldf(x, i, f);
        s[c] += v; q[c] += v*v;
    }
    __shared__ float red[6][256];
    int t = threadIdx.x;
    #pragma unroll
    for (int j = 0; j < 3; j++) { red[j][t] = s[j]; red[3+j][t] = q[j]; }
    __syncthreads();
    for (int st_ = 128; st_ > 0; st_ >>= 1) {
        if (t < st_) {
            #pragma unroll
            for (int j = 0; j < 6; j++) red[j][t] += red[j][t+st_];
        }
        __syncthreads();
    }
    if (t < 6) atomicAdd(&st[t], red[t][0]);
}

// ---------------- xb = bn1(input) ----------------
__global__ void k_xb_r8(const void* __restrict__ in, const int* __restrict__ dflag,
                        const float* __restrict__ st, float* __restrict__ xb)
{
    int f = *dflag;
    int i = blockIdx.x*256 + threadIdx.x;
    if (i >= TOT_X) return;
    int c = (i / NL) % 3;
    float m = st[c] * (1.0f/CNT_PER_C);
    float v = st[3+c] * (1.0f/CNT_PER_C) - m*m;
    xb[i] = (ldf(in, i, f) - m) / sqrtf(v + 1e-5f);
}

// ---------------- build XTa f32 (chunk-local b, n-major, 512) ----------------
__global__ void k_hid_r8(const float* __restrict__ xb, const void* __restrict__ mb,
                         const void* __restrict__ tide, const void* __restrict__ diwe,
                         const void* __restrict__ tsW, const void* __restrict__ tsb,
                         const int* __restrict__ tidx, const int* __restrict__ didx,
                         const int* __restrict__ dflag, int b0, float* __restrict__ XTa)
{
    int f = *dflag;
    int n = blockIdx.x, bl = blockIdx.y, bg = b0 + bl, t = threadIdx.x;
    __shared__ float xbs[36];
    if (t < 36) {
        int c = t / 12, l = t % 12;
        xbs[t] = xb[((bg*3 + c)*NN + n)*12 + l];
    }
    __syncthreads();
    float* dst = XTa + ((size_t)bl*NPAD + n)*HH;
    #pragma unroll
    for (int half = 0; half < 2; half++) {
        int ch = t + half*256;
        float v;
        if (ch < 128) {
            float acc = ldf(tsb, ch, f);
            #pragma unroll
            for (int k = 0; k < 36; k++) acc += xbs[k] * ldf(tsW, ch*36 + k, f);
            v = acc;
        } else if (ch < 256) v = ldf(mb, n*128 + ch - 128, f);
        else if (ch < 384) v = ldf(tide, tidx[bg]*128 + ch - 256, f);
        else v = ldf(diwe, didx[bg]*128 + ch - 384, f);
        dst[ch] = v;
    }
}

// ---------------- MFMA GEMM, bf16 hi/lo compensated (~f32 precision) ----------------
// A: weights from d_in (dual dtype), row-major (HO,512). B/out: f32 n-major acts.
template<bool RELU, bool RESID, bool F32OUT>
__global__ void __launch_bounds__(256)
k_gemm3_r8(const void* __restrict__ W, long Woff, const void* __restrict__ bias, long boff,
           const float* __restrict__ Xin, float* __restrict__ Xout,
           float* __restrict__ outF, const int* __restrict__ dflag, int HO, int b0)
{
    // LDS shorts: Ahi[0,4096) Alo[4096,8192) Bhi[8192,12288) Blo[12288,16384)
    __shared__ __align__(16) short sm[16384];
    int f = *dflag;
    int tid = threadIdx.x;
    int bz = blockIdx.z;
    int n0 = blockIdx.x * 128;
    int ho0 = blockIdx.y * 128;
    int lane = tid & 63, wave = tid >> 6;
    int wm = wave & 1, wn = wave >> 1;
    int lm = lane & 15, quad = lane >> 4;

    f32x4 acc[4][4];
    #pragma unroll
    for (int i = 0; i < 4; i++)
        #pragma unroll
        for (int j = 0; j < 4; j++) acc[i][j] = (f32x4){0.f, 0.f, 0.f, 0.f};

    const float* xbase = Xin + (size_t)bz*NPAD*HH;

    for (int k0 = 0; k0 < 512; k0 += 32) {
        #pragma unroll
        for (int g = 0; g < 4; g++) {
            int slot = tid + g*256;                  // 0..1023
            int row = slot >> 3, kk = (slot & 7) * 4;
            // ---- A (weights, dual dtype) ----
            int rr = ho0 + row; if (rr >= HO) rr = HO - 1;
            float av[4];
            if (f) {
                float4 t4 = *(const float4*)((const float*)W + Woff + (size_t)rr*512 + k0 + kk);
                av[0]=t4.x; av[1]=t4.y; av[2]=t4.z; av[3]=t4.w;
            } else {
                const __hip_bfloat16* wp = (const __hip_bfloat16*)W + Woff + (size_t)rr*512 + k0 + kk;
                #pragma unroll
                for (int j = 0; j < 4; j++) av[j] = bf2f(wp[j]);
            }
            short4 ahi, alo;
            {
                short h0=bfbits(av[0]), h1=bfbits(av[1]), h2=bfbits(av[2]), h3=bfbits(av[3]);
                __hip_bfloat16 b0_, b1_, b2_, b3_;
                *(short*)&b0_=h0; *(short*)&b1_=h1; *(short*)&b2_=h2; *(short*)&b3_=h3;
                ahi = make_short4(h0,h1,h2,h3);
                alo = make_short4(bfbits(av[0]-bf2f(b0_)), bfbits(av[1]-bf2f(b1_)),
                                  bfbits(av[2]-bf2f(b2_)), bfbits(av[3]-bf2f(b3_)));
            }
            *(short4*)&sm[slot*4]        = ahi;
            *(short4*)&sm[4096 + slot*4] = alo;
            // ---- B (activations, f32) ----
            int nB = n0 + row; if (nB >= NN) nB = NN - 1;
            float4 x4 = *(const float4*)(xbase + (size_t)nB*HH + k0 + kk);
            float bv[4] = {x4.x, x4.y, x4.z, x4.w};
            short4 bhi, blo;
            {
                short h0=bfbits(bv[0]), h1=bfbits(bv[1]), h2=bfbits(bv[2]), h3=bfbits(bv[3]);
                __hip_bfloat16 b0_, b1_, b2_, b3_;
                *(short*)&b0_=h0; *(short*)&b1_=h1; *(short*)&b2_=h2; *(short*)&b3_=h3;
                bhi = make_short4(h0,h1,h2,h3);
                blo = make_short4(bfbits(bv[0]-bf2f(b0_)), bfbits(bv[1]-bf2f(b1_)),
                                  bfbits(bv[2]-bf2f(b2_)), bfbits(bv[3]-bf2f(b3_)));
            }
            *(short4*)&sm[8192  + slot*4] = bhi;
            *(short4*)&sm[12288 + slot*4] = blo;
        }
        __syncthreads();
        bf16x8 ah[4], al[4], bh[4], bl[4];
        #pragma unroll
        for (int mi = 0; mi < 4; mi++) {
            int o = (wm*64 + mi*16 + lm)*32 + quad*8;
            ah[mi] = *(const bf16x8*)&sm[o];
            al[mi] = *(const bf16x8*)&sm[4096 + o];
        }
        #pragma unroll
        for (int ni = 0; ni < 4; ni++) {
            int o = (wn*64 + ni*16 + lm)*32 + quad*8;
            bh[ni] = *(const bf16x8*)&sm[8192 + o];
            bl[ni] = *(const bf16x8*)&sm[12288 + o];
        }
        #pragma unroll
        for (int mi = 0; mi < 4; mi++)
            #pragma unroll
            for (int ni = 0; ni < 4; ni++) {
                acc[mi][ni] = __builtin_amdgcn_mfma_f32_16x16x32_bf16(ah[mi], bh[ni], acc[mi][ni], 0, 0, 0);
                acc[mi][ni] = __builtin_amdgcn_mfma_f32_16x16x32_bf16(ah[mi], bl[ni], acc[mi][ni], 0, 0, 0);
                acc[mi][ni] = __builtin_amdgcn_mfma_f32_16x16x32_bf16(al[mi], bh[ni], acc[mi][ni], 0, 0, 0);
            }
        __syncthreads();
    }

    // epilogue: C/D col(n)=lane&15, row(ho)=quad*4+r
    #pragma unroll
    for (int mi = 0; mi < 4; mi++) {
        int hor = ho0 + wm*64 + mi*16 + quad*4;
        float bv[4];
        #pragma unroll
        for (int r = 0; r < 4; r++) {
            int h = hor + r; if (h >= HO) h = HO - 1;
            bv[r] = ldf(bias, boff + h, f);
        }
        #pragma unroll
        for (int ni = 0; ni < 4; ni++) {
            int nc = n0 + wn*64 + ni*16 + lm;
            if (nc >= NN) continue;
            if constexpr (F32OUT) {
                #pragma unroll
                for (int r = 0; r < 4; r++) {
                    int h = hor + r;
                    if (h < HO) outF[((size_t)(b0 + bz)*HO + h)*NN + nc] = acc[mi][ni][r] + bv[r];
                }
            } else {
                float* op = Xout + ((size_t)bz*NPAD + nc)*HH + hor;
                float4 vals;
                vals.x = acc[mi][ni][0] + bv[0];
                vals.y = acc[mi][ni][1] + bv[1];
                vals.z = acc[mi][ni][2] + bv[2];
                vals.w = acc[mi][ni][3] + bv[3];
                if constexpr (RESID) {
                    float4 rv = *(const float4*)op;
                    vals.x += rv.x; vals.y += rv.y; vals.z += rv.z; vals.w += rv.w;
                }
                if constexpr (RELU) {
                    vals.x = fmaxf(vals.x, 0.f); vals.y = fmaxf(vals.y, 0.f);
                    vals.z = fmaxf(vals.z, 0.f); vals.w = fmaxf(vals.w, 0.f);
                }
                *(float4*)op = vals;
            }
        }
    }
}

// ---------------- MFMA self-check: layer-0 gemm1, chunk-local b=0 ----------------
__global__ void __launch_bounds__(256)
k_check_r8(const void* __restrict__ W1, const void* __restrict__ B1,
           const int* __restrict__ dflag, const float* __restrict__ Xa,
           const float* __restrict__ Xb, int* __restrict__ bad)
{
    int f = *dflag;
    int n = blockIdx.x, t = threadIdx.x;
    __shared__ float xs[512];
    for (int k = t; k < 512; k += 256) xs[k] = Xa[(size_t)n*HH + k];
    __syncthreads();
    int fail = 0;
    #pragma unroll
    for (int half = 0; half < 2; half++) {
        int ho = t + half*256;
        float acc = ldf(B1, ho, f);
        for (int k = 0; k < 512; k++) acc += ldf(W1, (long)ho*512 + k, f) * xs[k];
        acc = fmaxf(acc, 0.f);
        float got = Xb[(size_t)n*HH + ho];
        if (fabsf(got - acc) > 0.1f + 0.01f*fabsf(acc)) fail = 1;
    }
    if (fail) atomicOr(bad, 1);
}

// ---------------- fallback VALU encoder (runs only if *bad) ----------------
__global__ void __launch_bounds__(256)
k_encfb_r8(const float* __restrict__ xb, const void* __restrict__ mb,
           const void* __restrict__ tide, const void* __restrict__ diwe,
           const void* __restrict__ tsW, const void* __restrict__ tsb,
           const void* __restrict__ W1, const void* __restrict__ B1,
           const void* __restrict__ W2, const void* __restrict__ B2,
           const void* __restrict__ regW, const void* __restrict__ regB,
           const int* __restrict__ tidx, const int* __restrict__ didx,
           const int* __restrict__ dflag, const int* __restrict__ bad,
           float* __restrict__ regb)
{
    if (*bad == 0) return;
    int f = *dflag;
    int n = blockIdx.x, b = blockIdx.y, t = threadIdx.x;
    __shared__ float h[512], hn[512], xbs[36];
    if (t < 36) {
        int c = t / 12, l = t % 12;
        xbs[t] = xb[((b*3 + c)*NN + n)*12 + l];
    }
    __syncthreads();
    #pragma unroll
    for (int half = 0; half < 2; half++) {
        int ch = t + half*256;
        float v;
        if (ch < 128) {
            float acc = ldf(tsb, ch, f);
            for (int k = 0; k < 36; k++) acc += xbs[k] * ldf(tsW, ch*36 + k, f);
            v = acc;
        } else if (ch < 256) v = ldf(mb, n*128 + ch - 128, f);
        else if (ch < 384) v = ldf(tide, tidx[b]*128 + ch - 256, f);
        else v = ldf(diwe, didx[b]*128 + ch - 384, f);
        h[ch] = v;
    }
    __syncthreads();
    for (int i = 0; i < 3; i++) {
        #pragma unroll
        for (int half = 0; half < 2; half++) {
            int ho = t + half*256;
            float acc = ldf(B1, i*512 + ho, f);
            long base = (long)(i*512 + ho)*512;
            for (int k = 0; k < 512; k++) acc += ldf(W1, base + k, f) * h[k];
            hn[ho] = fmaxf(acc, 0.f);
        }
        __syncthreads();
        float upd[2];
        #pragma unroll
        for (int half = 0; half < 2; half++) {
            int ho = t + half*256;
            float acc = ldf(B2, i*512 + ho, f);
            long base = (long)(i*512 + ho)*512;
            for (int k = 0; k < 512; k++) acc += ldf(W2, base + k, f) * hn[k];
            upd[half] = acc;
        }
        __syncthreads();
        #pragma unroll
        for (int half = 0; half < 2; half++) { int ho = t + half*256; h[ho] += upd[half]; }
        __syncthreads();
    }
    if (t < 36) {
        float acc = ldf(regB, t, f);
        for (int k = 0; k < 512; k++) acc += ldf(regW, (long)t*512 + k, f) * h[k];
        regb[((size_t)b*36 + t)*NN + n] = acc;
    }
}

// ---------------- bn2 stats over reg (B,36,N) ----------------
__global__ void k_bn2_r8(const float* __restrict__ x, float* __restrict__ st)
{
    float s[3] = {0,0,0}, q[3] = {0,0,0};
    for (int i = blockIdx.x*256 + threadIdx.x; i < TOT_X; i += 512*256) {
        int c = ((i / NN) % 36) / 12;
        float v = x[i];
        s[c] += v; q[c] += v*v;
    }
    __shared__ float red[6][256];
    int t = threadIdx.x;
    #pragma unroll
    for (int j = 0; j < 3; j++) { red[j][t] = s[j]; red[3+j][t] = q[j]; }
    __syncthreads();
    for (int st_ = 128; st_ > 0; st_ >>= 1) {
        if (t < st_) {
            #pragma unroll
            for (int j = 0; j < 6; j++) red[j][t] += red[j][t+st_];
        }
        __syncthreads();
    }
    if (t < 6) atomicAdd(&st[t], red[t][0]);
}

// ---------------- xpre = bn2(hid) + conv(xb); bn3 stats ----------------
__global__ void k_xpre_r8(const float* __restrict__ regb, const float* __restrict__ xb,
                          const void* __restrict__ convW, const void* __restrict__ convb,
                          const int* __restrict__ dflag,
                          const float* __restrict__ st2, float* __restrict__ st3,
                          float* __restrict__ xpre)
{
    int f = *dflag;
    int i = blockIdx.x*256 + threadIdx.x;
    float s[3] = {0,0,0}, q[3] = {0,0,0};
    if (i < TOT_X) {
        int b = i / 31788, r1 = i % 31788;
        int c = r1 / NL, r2 = r1 % NL;
        int n = r2 / 12, l = r2 % 12;
        float m2 = st2[c] * (1.0f/CNT_PER_C);
        float v2 = st2[3+c] * (1.0f/CNT_PER_C) - m2*m2;
        float hidv = (regb[((size_t)b*36 + c*12 + l)*NN + n] - m2) / sqrtf(v2 + 1e-5f);
        float cx = ldf(convb, c, f);
        #pragma unroll
        for (int cc = 0; cc < 3; cc++)
            cx += ldf(convW, c*3 + cc, f) * xb[((b*3 + cc)*NN + n)*12 + l];
        float v = hidv + cx;
        xpre[i] = v;
        s[c] = v; q[c] = v*v;
    }
    __shared__ float red[6][256];
    int t = threadIdx.x;
    #pragma unroll
    for (int j = 0; j < 3; j++) { red[j][t] = s[j]; red[3+j][t] = q[j]; }
    __syncthreads();
    for (int st_ = 128; st_ > 0; st_ >>= 1) {
        if (t < st_) {
            #pragma unroll
            for (int j = 0; j < 6; j++) red[j][t] += red[j][t+st_];
        }
        __syncthreads();
    }
    if (t < 6) atomicAdd(&st3[t], red[t][0]);
}

// ---------------- naive tail per (b,n) ----------------
__global__ void __launch_bounds__(64)
k_tail_r8(const float* __restrict__ xpre, const float* __restrict__ st3,
          const float* __restrict__ phi, const float* __restrict__ topval,
          const int* __restrict__ topidx,
          const void* __restrict__ wie, const void* __restrict__ mixp,
          const void* __restrict__ fusW, const void* __restrict__ fusb,
          const void* __restrict__ g1W, const void* __restrict__ g1b,
          const void* __restrict__ g2W, const void* __restrict__ g2b,
          const int* __restrict__ dflag, float* __restrict__ out)
{
    int f = *dflag;
    int n = blockIdx.x, b = blockIdx.y, t = threadIdx.x;
    __shared__ float xe[3][10][12], mn[3][10], phis[24], ws[10];
    __shared__ float pm[3][10][12], pred[3][12], pred2[128][12];
    float m3[3], rs3[3];
    #pragma unroll
    for (int c = 0; c < 3; c++) {
        float m = st3[c] * (1.0f/CNT_PER_C);
        float v = st3[3+c] * (1.0f/CNT_PER_C) - m*m;
        m3[c] = m; rs3[c] = 1.0f / sqrtf(v + 1e-5f);
    }
    if (t < 24) phis[t] = phi[b*24 + t];
    if (t < 10) ws[t] = (t == 0 ? 1.0f : topval[n*9 + t - 1]) * ldf(wie, t, f);
    for (int i = t; i < 360; i += 64) {
        int c = i / 120, m = (i / 12) % 10, l = i % 12;
        int nn2 = (m == 0) ? n : topidx[n*9 + m - 1];
        xe[c][m][l] = (xpre[((size_t)(b*3 + c)*NN + nn2)*12 + l] - m3[c]) * rs3[c];
    }
    __syncthreads();
    if (t < 30) {
        int c = t / 10, m = t % 10;
        float s = 0.f;
        #pragma unroll
        for (int l = 0; l < 12; l++) s += xe[c][m][l];
        mn[c][m] = s * (1.0f/12.0f);
    }
    __syncthreads();
    float mix = ldf(mixp, 0, f);
    for (int pr = t; pr < 120; pr += 64) {
        int m = pr / 12, p = pr % 12;
        float y[3], sc[12], mx = -3.4e38f;
        #pragma unroll
        for (int c = 0; c < 3; c++) y[c] = phis[12+p] + mix*mn[c][m];
        #pragma unroll
        for (int l = 0; l < 12; l++) {
            float v = 0.f;
            #pragma unroll
            for (int c = 0; c < 3; c++) v += y[c] * (phis[l] + mix*mn[c][m]);
            sc[l] = v * (1.0f/36.0f); mx = fmaxf(mx, sc[l]);
        }
        float den = 0.f;
        #pragma unroll
        for (int l = 0; l < 12; l++) { float e = expf(sc[l] - mx); sc[l] = e; den += e; }
        float inv = 1.0f/den;
        float p0 = 0.f, p1 = 0.f, p2 = 0.f;
        #pragma unroll
        for (int l = 0; l < 12; l++) {
            float a = sc[l]*inv;
            p0 += a*xe[0][m][l]; p1 += a*xe[1][m][l]; p2 += a*xe[2][m][l];
        }
        pm[0][m][p] = p0; pm[1][m][p] = p1; pm[2][m][p] = p2;
    }
    __syncthreads();
    if (t < 36) {
        int c = t/12, p = t%12;
        float s = 0.f;
        #pragma unroll
        for (int m = 0; m < 10; m++) s += pm[c][m][p]*ws[m];
        pred[c][p] = s;
    }
    __syncthreads();
    for (int i = t; i < 1536; i += 64) {
        int d = i / 12, p = i % 12;
        float s = ldf(fusb, d, f);
        #pragma unroll
        for (int c = 0; c < 3; c++) s += pred[c][p] * ldf(fusW, c*128 + d, f);
        pred2[d][p] = s;
    }
    __syncthreads();
    if (t < 36) {
        int o = t/12, p = t%12;
        float o1 = ldf(g1b, o, f), o2 = ldf(g2b, o, f);
        for (int d = 0; d < 128; d++) {
            o1 += pred2[d][p] * ldf(g1W, d*3 + o, f);
            o2 += pred2[d][p] * ldf(g2W, d*3 + o, f);
        }
        out[((size_t)(b*3 + o)*NN + n)*12 + p] = o1 / (1.0f + expf(-o2));
    }
}

// ---------------------------------------------------------------------------
extern "C" void kernel_launch(void* const* d_in, const int* in_sizes, int n_in,
                              void* d_out, int out_size, void* d_ws, size_t ws_size,
                              hipStream_t stream)
{
    (void)in_sizes; (void)n_in;
    char* w = (char*)d_ws;
    auto alloc = [&](size_t bytes) { char* p = w; w += (bytes + 255) & ~(size_t)255; return p; };

    // fixed (~12.4 MB)
    float* xb     = (float*)alloc((size_t)TOT_X*4);
    float* regb   = (float*)alloc((size_t)TOT_X*4);
    float* xpre   = (float*)alloc((size_t)TOT_X*4);
    float* phi    = (float*)alloc(768*4);
    float* topval = (float*)alloc(7947*4);
    int*   topidx = (int*)alloc(7947*4);
    int*   tidx   = (int*)alloc(32*4);
    int*   didx   = (int*)alloc(32*4);
    float* stats  = (float*)alloc(18*4);  // bn1|bn2|bn3
    int*   dflag  = (int*)alloc(4);
    int*   bad    = (int*)alloc(4);
    size_t fixedEnd = (size_t)(w - (char*)d_ws);

    const size_t XTB = (size_t)NPAD*HH*4;                 // 1,835,008 B per batch elem
    const size_t graphBytes = 452352*2 + 3118848;         // e1,e2,amat (256-aligned)
    int CH = 0;
    for (int c = 32; c >= 1; c >>= 1) {
        size_t regB = 2*(size_t)c*XTB; if (regB < graphBytes) regB = graphBytes;
        if (fixedEnd + regB + 4096 <= ws_size) { CH = c; break; }
    }
    if (CH == 0) {
        k_sent_r8<<<(out_size + 255)/256, 256, 0, stream>>>((float*)d_out, out_size);
        return;
    }
    char* regionB = w;
    float* e1   = (float*)regionB;
    float* e2   = (float*)(regionB + 452352);
    float* amat = (float*)(regionB + 904704);
    float* XTa  = (float*)regionB;
    float* XTb  = (float*)(regionB + (size_t)CH*XTB);

    hipMemsetAsync(stats, 0, 18*4, stream);
    hipMemsetAsync(bad, 0, 4, stream);

    k_probe_r8<<<1, 256, 0, stream>>>((const unsigned short*)d_in[0], dflag);
    k_prep_r8<<<1, 256, 0, stream>>>(d_in[2], d_in[3], d_in[19], d_in[20], d_in[21], d_in[22],
                                     dflag, tidx, didx, phi);
    // graph phase (uses regionB as e1/e2/amat; done before encoder reuses it)
    k_e_r8<<<883, 256, 0, stream>>>(d_in[4], d_in[5], d_in[6], dflag, e1, e2);
    k_amat_r8<<<3047, 256, 0, stream>>>(e1, e2, amat);
    k_rowsm_r8<<<883, 256, 0, stream>>>(amat);
    k_top9_r8<<<883, 256, 0, stream>>>(amat, topval, topidx);
    k_bn1_r8<<<512, 256, 0, stream>>>(d_in[0], dflag, stats);
    k_xb_r8<<<3974, 256, 0, stream>>>(d_in[0], dflag, stats, xb);

    for (int b0 = 0; b0 < BB; b0 += CH) {
        k_hid_r8<<<dim3(NN, CH), 256, 0, stream>>>(xb, d_in[4], d_in[7], d_in[8], d_in[9],
                                                   d_in[10], tidx, didx, dflag, b0, XTa);
        for (int i = 0; i < 3; i++) {
            k_gemm3_r8<true, false, false><<<dim3(7, 4, CH), 256, 0, stream>>>(
                d_in[13], (long)i*HH*HH, d_in[14], (long)i*HH, XTa, XTb,
                (float*)nullptr, dflag, HH, b0);
            if (b0 == 0 && i == 0)
                k_check_r8<<<NN, 256, 0, stream>>>(d_in[13], d_in[14], dflag, XTa, XTb, bad);
            k_gemm3_r8<false, true, false><<<dim3(7, 4, CH), 256, 0, stream>>>(
                d_in[15], (long)i*HH*HH, d_in[16], (long)i*HH, XTb, XTa,
                (float*)nullptr, dflag, HH, b0);
        }
        k_gemm3_r8<false, false, true><<<dim3(7, 1, CH), 256, 0, stream>>>(
            d_in[17], 0, d_in[18], 0, XTa, (float*)nullptr, regb, dflag, 36, b0);
    }

    // fallback (no-op when check clean)
    k_encfb_r8<<<dim3(NN, BB), 256, 0, stream>>>(xb, d_in[4], d_in[7], d_in[8], d_in[9],
                                                 d_in[10], d_in[13], d_in[14], d_in[15],
                                                 d_in[16], d_in[17], d_in[18], tidx, didx,
                                                 dflag, bad, regb);

    k_bn2_r8<<<512, 256, 0, stream>>>(regb, stats + 6);
    k_xpre_r8<<<3974, 256, 0, stream>>>(regb, xb, d_in[11], d_in[12], dflag,
                                        stats + 6, stats + 12, xpre);
    k_tail_r8<<<dim3(NN, BB), 64, 0, stream>>>(xpre, stats + 12, phi, topval, topidx,
                                               d_in[24], d_in[23], d_in[25], d_in[26],
                                               d_in[27], d_in[28], d_in[29], d_in[30],
                                               dflag, (float*)d_out);
}

// Round 9
// 1078.761 us; speedup vs baseline: 78.9787x; 1.6583x over previous
//
#include <hip/hip_runtime.h>
#include <hip/hip_bf16.h>

// ---------------------------------------------------------------------------
// STD2Vformer forward, MI355X. Round 9 (R8 passed @1.789ms):
//  - check/fallback removed (MFMA layout HW-verified R8, absmax 1.2e-4)
//  - weights pre-split to bf16 hi/lo once; activations stored as (hi,lo) pairs
//    -> gemm K-loop staging is pure int4 copies (no per-element VALU split)
//  - LDS row stride 40 shorts (80B): bank-conflict-free ds_read_b128/write_b128
//  - GLU precombined to 3x3 (wc) -> light tail
// ---------------------------------------------------------------------------

#define NN 883
#define NPAD 896
#define BB 32
#define HH 512
#define NL 10596            // N*L
#define CNT_PER_C 339072.0f // B*N*L
#define TOT_X 1017216       // B*C*N*L
#define AMAT_N 779689       // N*N
#define LSTR 40             // LDS row stride in shorts (80B, 16B-aligned, conflict-free)
#define LREG 5120           // shorts per LDS operand region (128*LSTR)

typedef __attribute__((ext_vector_type(8))) short bf16x8;
typedef __attribute__((ext_vector_type(4))) float f32x4;

static __device__ __forceinline__ float bf2f(__hip_bfloat16 v) { return __bfloat162float(v); }
static __device__ __forceinline__ float ldf(const void* p, long i, int f) {
    return f ? ((const float*)p)[i] : bf2f(((const __hip_bfloat16*)p)[i]);
}

struct alignas(8) BF4 { __hip_bfloat16 a, b, c, d; };

// ---------------- sentinel ----------------
__global__ void k_sent_r9(float* __restrict__ out, int n)
{
    int i = blockIdx.x*256 + threadIdx.x;
    if (i < n) out[i] = 1000.0f;
}

// ---------------- input dtype probe ----------------
__global__ void k_probe_r9(const unsigned short* __restrict__ u, int* __restrict__ flag)
{
    int t = threadIdx.x, cnt = 0;
    for (int i = t; i < 4096; i += 256) {
        int e = (u[i] >> 7) & 0xFF;
        cnt += (e >= 0xC0);
    }
    __shared__ int r[256];
    r[t] = cnt; __syncthreads();
    for (int s = 128; s > 0; s >>= 1) { if (t < s) r[t] += r[t+s]; __syncthreads(); }
    if (t == 0) *flag = (r[0] > 8) ? 1 : 0;
}

// ---------------- weight hi/lo split ----------------
__global__ void k_wsplit_r9(const void* __restrict__ src, const int* __restrict__ dflag,
                            int n, __hip_bfloat16* __restrict__ hi,
                            __hip_bfloat16* __restrict__ lo)
{
    int f = *dflag;
    for (int i = blockIdx.x*256 + threadIdx.x; i < n; i += gridDim.x*256) {
        float v = ldf(src, i, f);
        __hip_bfloat16 h = __float2bfloat16(v);
        hi[i] = h;
        lo[i] = __float2bfloat16(v - bf2f(h));
    }
}

// ---------------- prep: tidx, didx, phi(B,24), wc (combined GLU 3x3) ----------------
__global__ void k_prep_r9(const void* __restrict__ seqs, const void* __restrict__ tgts,
                          const void* __restrict__ w0, const void* __restrict__ b0,
                          const void* __restrict__ d2vW, const void* __restrict__ d2vb,
                          const void* __restrict__ fusW, const void* __restrict__ fusb,
                          const void* __restrict__ g1W, const void* __restrict__ g1b,
                          const void* __restrict__ g2W, const void* __restrict__ g2b,
                          const int* __restrict__ dflag,
                          int* __restrict__ tidx, int* __restrict__ didx,
                          float* __restrict__ phi, float* __restrict__ wc)
{
    int f = *dflag, t = threadIdx.x;
    if (t < 32) {
        int b = t;
        float h  = (ldf(seqs, (b*5+3)*12 + 11, f) + 0.5f) * 23.0f;
        float mi = (ldf(seqs, (b*5+4)*12 + 11, f) + 0.5f) * 59.0f;
        int ti = (int)((h * 60.0f + mi) / 5.0f);
        tidx[b] = ti < 0 ? 0 : (ti > 287 ? 287 : ti);
        int di = (int)((ldf(seqs, (b*5+2)*12 + 11, f) + 0.5f) * 6.0f);
        didx[b] = di < 0 ? 0 : (di > 6 ? 6 : di);
    }
    for (int i = t; i < 768; i += 256) {
        int b = i / 24, tt = i % 24;
        float tau[5];
        #pragma unroll
        for (int d = 0; d < 5; d++)
            tau[d] = (tt < 12) ? ldf(seqs, (b*5+d)*12 + tt, f)
                               : ldf(tgts, (b*5+d)*12 + tt - 12, f);
        float s = ldf(b0, 0, f);
        #pragma unroll
        for (int d = 0; d < 5; d++) s += tau[d] * ldf(w0, d, f);
        for (int k = 0; k < 16; k++) {
            float arg = ldf(d2vb, k, f);
            #pragma unroll
            for (int d = 0; d < 5; d++) arg += tau[d] * ldf(d2vW, k*5 + d, f);
            s += sinf(arg);
        }
        phi[i] = s;
    }
    if (t < 24) {
        if (t < 9) {                      // wc1[o*3+c] = sum_d fusW[c,d]*g1W[d,o]
            int o = t / 3, c = t % 3; float s = 0.f;
            for (int d = 0; d < 128; d++) s += ldf(fusW, c*128+d, f) * ldf(g1W, d*3+o, f);
            wc[t] = s;
        } else if (t < 12) {              // bc1
            int o = t - 9; float s = ldf(g1b, o, f);
            for (int d = 0; d < 128; d++) s += ldf(fusb, d, f) * ldf(g1W, d*3+o, f);
            wc[9 + o] = s;
        } else if (t < 21) {              // wc2
            int j = t - 12; int o = j / 3, c = j % 3; float s = 0.f;
            for (int d = 0; d < 128; d++) s += ldf(fusW, c*128+d, f) * ldf(g2W, d*3+o, f);
            wc[12 + j] = s;
        } else {                          // bc2
            int o = t - 21; float s = ldf(g2b, o, f);
            for (int d = 0; d < 128; d++) s += ldf(fusb, d, f) * ldf(g2W, d*3+o, f);
            wc[21 + o] = s;
        }
    }
}

// ---------------- e1 = mb@We1, e2 = mb@We2 ----------------
__global__ void k_e_r9(const void* __restrict__ mb, const void* __restrict__ We1,
                       const void* __restrict__ We2, const int* __restrict__ dflag,
                       float* __restrict__ e1, float* __restrict__ e2)
{
    int f = *dflag;
    int idx = blockIdx.x*256 + threadIdx.x;
    int which = idx >= 113024;
    int j = which ? idx - 113024 : idx;
    int d = j & 127, n = j >> 7;
    const void* W = which ? We2 : We1;
    float s = 0.f;
    for (int k = 0; k < 128; k++)
        s += ldf(mb, n*128 + k, f) * ldf(W, k*128 + d, f);
    (which ? e2 : e1)[j] = s;
}

// ---------------- a[n,m] = e1[n]·e2[m] ----------------
__global__ void k_amat_r9(const float* __restrict__ e1, const float* __restrict__ e2,
                          float* __restrict__ amat)
{
    int i = blockIdx.x*256 + threadIdx.x;
    if (i >= AMAT_N) return;
    int n = i / NN, m = i % NN;
    float s = 0.f;
    for (int k = 0; k < 128; k++) s += e1[n*128 + k] * e2[m*128 + k];
    amat[i] = s;
}

// ---- per-row: standardize(ddof=1), relu, diag-mask, softmax in place ----
__global__ void k_rowsm_r9(float* __restrict__ amat)
{
    int n = blockIdx.x, t = threadIdx.x;
    __shared__ float arow[NN];
    __shared__ float red[256];
    for (int m = t; m < NN; m += 256) arow[m] = amat[n*NN + m];
    __syncthreads();
    float s = 0.f;
    for (int m = t; m < NN; m += 256) s += arow[m];
    red[t] = s; __syncthreads();
    for (int st = 128; st > 0; st >>= 1) { if (t < st) red[t] += red[t+st]; __syncthreads(); }
    float mean = red[0] / 883.0f; __syncthreads();
    float ss = 0.f;
    for (int m = t; m < NN; m += 256) { float d = arow[m] - mean; ss += d*d; }
    red[t] = ss; __syncthreads();
    for (int st = 128; st > 0; st >>= 1) { if (t < st) red[t] += red[t+st]; __syncthreads(); }
    float rstd = 1.0f / sqrtf(red[0] / 882.0f); __syncthreads();
    for (int m = t; m < NN; m += 256) {
        float z = (arow[m] - mean) * rstd;
        z = fmaxf(z, 0.f);
        if (m == n) z -= 1e6f;
        arow[m] = z;
    }
    __syncthreads();
    float mx = -3.4e38f;
    for (int m = t; m < NN; m += 256) mx = fmaxf(mx, arow[m]);
    red[t] = mx; __syncthreads();
    for (int st = 128; st > 0; st >>= 1) { if (t < st) red[t] = fmaxf(red[t], red[t+st]); __syncthreads(); }
    float M = red[0]; __syncthreads();
    float ds = 0.f;
    for (int m = t; m < NN; m += 256) { float e = expf(arow[m] - M); arow[m] = e; ds += e; }
    red[t] = ds; __syncthreads();
    for (int st = 128; st > 0; st >>= 1) { if (t < st) red[t] += red[t+st]; __syncthreads(); }
    float inv = 1.0f / red[0]; __syncthreads();
    for (int m = t; m < NN; m += 256) amat[n*NN + m] = arow[m] * inv;
}

// ---------------- top-9 per row ----------------
__global__ void k_top9_r9(const float* __restrict__ amat,
                          float* __restrict__ topval, int* __restrict__ topidx)
{
    int n = blockIdx.x, t = threadIdx.x;
    __shared__ float arow[NN];
    __shared__ float red[256];
    __shared__ int redi[256];
    for (int m = t; m < NN; m += 256) arow[m] = amat[n*NN + m];
    __syncthreads();
    for (int j = 0; j < 9; j++) {
        float bv = -1.f; int bi = 0;
        for (int m = t; m < NN; m += 256) { float v = arow[m]; if (v > bv) { bv = v; bi = m; } }
        red[t] = bv; redi[t] = bi; __syncthreads();
        for (int st = 128; st > 0; st >>= 1) {
            if (t < st) {
                float ov = red[t+st]; int oi = redi[t+st];
                if (ov > red[t] || (ov == red[t] && oi < redi[t])) { red[t] = ov; redi[t] = oi; }
            }
            __syncthreads();
        }
        if (t == 0) {
            topval[n*9 + j] = red[0];
            topidx[n*9 + j] = redi[0];
            arow[redi[0]] = -1.f;
        }
        __syncthreads();
    }
}

// ---------------- bn1 stats ----------------
__global__ void k_bn1_r9(const void* __restrict__ x, const int* __restrict__ dflag,
                         float* __restrict__ st)
{
    int f = *dflag;
    float s[3] = {0,0,0}, q[3] = {0,0,0};
    for (int i = blockIdx.x*256 + threadIdx.x; i < TOT_X; i += 512*256) {
        int c = (i / NL) % 3;
        float v = ldf(x, i, f);
        s[c] += v; q[c] += v*v;
    }
    __shared__ float red[6][256];
    int t = threadIdx.x;
    #pragma unroll
    for (int j = 0; j < 3; j++) { red[j][t] = s[j]; red[3+j][t] = q[j]; }
    __syncthreads();
    for (int st_ = 128; st_ > 0; st_ >>= 1) {
        if (t < st_) {
            #pragma unroll
            for (int j = 0; j < 6; j++) red[j][t] += red[j][t+st_];
        }
        __syncthreads();
    }
    if (t < 6) atomicAdd(&st[t], red[t][0]);
}

// ---------------- xb = bn1(input) ----------------
__global__ void k_xb_r9(const void* __restrict__ in, const int* __restrict__ dflag,
                        const float* __restrict__ st, float* __restrict__ xb)
{
    int f = *dflag;
    int i = blockIdx.x*256 + threadIdx.x;
    if (i >= TOT_X) return;
    int c = (i / NL) % 3;
    float m = st[c] * (1.0f/CNT_PER_C);
    float v = st[3+c] * (1.0f/CNT_PER_C) - m*m;
    xb[i] = (ldf(in, i, f) - m) / sqrtf(v + 1e-5f);
}

// ---------------- build hidden as (hi,lo) bf16 pair (chunk-local b, n-major) ----------------
__global__ void k_hid_r9(const float* __restrict__ xb, const void* __restrict__ mb,
                         const void* __restrict__ tide, const void* __restrict__ diwe,
                         const void* __restrict__ tsW, const void* __restrict__ tsb,
                         const int* __restrict__ tidx, const int* __restrict__ didx,
                         const int* __restrict__ dflag, int b0,
                         __hip_bfloat16* __restrict__ Xhi, __hip_bfloat16* __restrict__ Xlo)
{
    int f = *dflag;
    int n = blockIdx.x, bl = blockIdx.y, bg = b0 + bl, t = threadIdx.x;
    __shared__ float xbs[36];
    if (t < 36) {
        int c = t / 12, l = t % 12;
        xbs[t] = xb[((bg*3 + c)*NN + n)*12 + l];
    }
    __syncthreads();
    size_t base = ((size_t)bl*NPAD + n)*HH;
    #pragma unroll
    for (int half = 0; half < 2; half++) {
        int ch = t + half*256;
        float v;
        if (ch < 128) {
            float acc = ldf(tsb, ch, f);
            #pragma unroll
            for (int k = 0; k < 36; k++) acc += xbs[k] * ldf(tsW, ch*36 + k, f);
            v = acc;
        } else if (ch < 256) v = ldf(mb, n*128 + ch - 128, f);
        else if (ch < 384) v = ldf(tide, tidx[bg]*128 + ch - 256, f);
        else v = ldf(diwe, didx[bg]*128 + ch - 384, f);
        __hip_bfloat16 h = __float2bfloat16(v);
        Xhi[base + ch] = h;
        Xlo[base + ch] = __float2bfloat16(v - bf2f(h));
    }
}

// ---------------- MFMA GEMM: pre-split hi/lo operands, 3 MFMAs/frag ----------------
template<bool RELU, bool RESID, bool F32OUT>
__global__ void __launch_bounds__(256)
k_gemm_r9(const __hip_bfloat16* __restrict__ Whi, const __hip_bfloat16* __restrict__ Wlo,
          long Woff, const void* __restrict__ bias, long boff,
          const int* __restrict__ dflag,
          const __hip_bfloat16* __restrict__ Xhi, const __hip_bfloat16* __restrict__ Xlo,
          __hip_bfloat16* __restrict__ Yhi, __hip_bfloat16* __restrict__ Ylo,
          float* __restrict__ outF, int HO, int b0)
{
    __shared__ __align__(16) short sm[4*LREG];  // Ahi|Alo|Bhi|Blo, stride-40 rows
    int tid = threadIdx.x, bz = blockIdx.z;
    int n0 = blockIdx.x * 128, ho0 = blockIdx.y * 128;
    int lane = tid & 63, wave = tid >> 6;
    int wm = wave & 1, wn = wave >> 1;
    int lm = lane & 15, quad = lane >> 4;

    f32x4 acc[4][4];
    #pragma unroll
    for (int i = 0; i < 4; i++)
        #pragma unroll
        for (int j = 0; j < 4; j++) acc[i][j] = (f32x4){0.f, 0.f, 0.f, 0.f};

    const size_t xb0 = (size_t)bz*NPAD*HH;

    for (int k0 = 0; k0 < 512; k0 += 32) {
        #pragma unroll
        for (int it = 0; it < 2; it++) {
            int s = it*256 + tid;                    // 0..511
            int row = s >> 2, kc = (s & 3)*8;
            int rr = ho0 + row; if (rr >= HO) rr = HO - 1;
            size_t wofs = Woff + (size_t)rr*512 + k0 + kc;
            int4 va_hi = *(const int4*)(Whi + wofs);
            int4 va_lo = *(const int4*)(Wlo + wofs);
            int nB = n0 + row; if (nB >= NN) nB = NN - 1;
            size_t xofs = xb0 + (size_t)nB*HH + k0 + kc;
            int4 vb_hi = *(const int4*)(Xhi + xofs);
            int4 vb_lo = *(const int4*)(Xlo + xofs);
            int lofs = row*LSTR + kc;
            *(int4*)&sm[lofs]          = va_hi;
            *(int4*)&sm[LREG + lofs]   = va_lo;
            *(int4*)&sm[2*LREG + lofs] = vb_hi;
            *(int4*)&sm[3*LREG + lofs] = vb_lo;
        }
        __syncthreads();
        bf16x8 ah[4], al[4], bh[4], bl[4];
        #pragma unroll
        for (int mi = 0; mi < 4; mi++) {
            int o = (wm*64 + mi*16 + lm)*LSTR + quad*8;
            ah[mi] = *(const bf16x8*)&sm[o];
            al[mi] = *(const bf16x8*)&sm[LREG + o];
        }
        #pragma unroll
        for (int ni = 0; ni < 4; ni++) {
            int o = (wn*64 + ni*16 + lm)*LSTR + quad*8;
            bh[ni] = *(const bf16x8*)&sm[2*LREG + o];
            bl[ni] = *(const bf16x8*)&sm[3*LREG + o];
        }
        #pragma unroll
        for (int mi = 0; mi < 4; mi++)
            #pragma unroll
            for (int ni = 0; ni < 4; ni++) {
                acc[mi][ni] = __builtin_amdgcn_mfma_f32_16x16x32_bf16(ah[mi], bh[ni], acc[mi][ni], 0, 0, 0);
                acc[mi][ni] = __builtin_amdgcn_mfma_f32_16x16x32_bf16(ah[mi], bl[ni], acc[mi][ni], 0, 0, 0);
                acc[mi][ni] = __builtin_amdgcn_mfma_f32_16x16x32_bf16(al[mi], bh[ni], acc[mi][ni], 0, 0, 0);
            }
        __syncthreads();
    }

    int f = *dflag;
    // epilogue: C/D col(n)=lane&15, row(ho)=quad*4+r  [HW-verified R8]
    #pragma unroll
    for (int mi = 0; mi < 4; mi++) {
        int hor = ho0 + wm*64 + mi*16 + quad*4;
        float bv[4];
        #pragma unroll
        for (int r = 0; r < 4; r++) {
            int h = hor + r; if (h >= HO) h = HO - 1;
            bv[r] = ldf(bias, boff + h, f);
        }
        #pragma unroll
        for (int ni = 0; ni < 4; ni++) {
            int nc = n0 + wn*64 + ni*16 + lm;
            if (nc >= NN) continue;
            if constexpr (F32OUT) {
                #pragma unroll
                for (int r = 0; r < 4; r++) {
                    int h = hor + r;
                    if (h < HO) outF[((size_t)(b0 + bz)*HO + h)*NN + nc] = acc[mi][ni][r] + bv[r];
                }
            } else {
                size_t o = xb0 + (size_t)nc*HH + hor;
                float vals[4];
                #pragma unroll
                for (int r = 0; r < 4; r++) vals[r] = acc[mi][ni][r] + bv[r];
                if constexpr (RESID) {
                    BF4 rh = *(const BF4*)(Yhi + o);
                    BF4 rl = *(const BF4*)(Ylo + o);
                    vals[0] += bf2f(rh.a) + bf2f(rl.a);
                    vals[1] += bf2f(rh.b) + bf2f(rl.b);
                    vals[2] += bf2f(rh.c) + bf2f(rl.c);
                    vals[3] += bf2f(rh.d) + bf2f(rl.d);
                }
                if constexpr (RELU) {
                    #pragma unroll
                    for (int r = 0; r < 4; r++) vals[r] = fmaxf(vals[r], 0.f);
                }
                BF4 hi, lo;
                hi.a = __float2bfloat16(vals[0]); lo.a = __float2bfloat16(vals[0] - bf2f(hi.a));
                hi.b = __float2bfloat16(vals[1]); lo.b = __float2bfloat16(vals[1] - bf2f(hi.b));
                hi.c = __float2bfloat16(vals[2]); lo.c = __float2bfloat16(vals[2] - bf2f(hi.c));
                hi.d = __float2bfloat16(vals[3]); lo.d = __float2bfloat16(vals[3] - bf2f(hi.d));
                *(BF4*)(Yhi + o) = hi;
                *(BF4*)(Ylo + o) = lo;
            }
        }
    }
}

// ---------------- bn2 stats over reg (B,36,N) ----------------
__global__ void k_bn2_r9(const float* __restrict__ x, float* __restrict__ st)
{
    float s[3] = {0,0,0}, q[3] = {0,0,0};
    for (int i = blockIdx.x*256 + threadIdx.x; i < TOT_X; i += 512*256) {
        int c = ((i / NN) % 36) / 12;
        float v = x[i];
        s[c] += v; q[c] += v*v;
    }
    __shared__ float red[6][256];
    int t = threadIdx.x;
    #pragma unroll
    for (int j = 0; j < 3; j++) { red[j][t] = s[j]; red[3+j][t] = q[j]; }
    __syncthreads();
    for (int st_ = 128; st_ > 0; st_ >>= 1) {
        if (t < st_) {
            #pragma unroll
            for (int j = 0; j < 6; j++) red[j][t] += red[j][t+st_];
        }
        __syncthreads();
    }
    if (t < 6) atomicAdd(&st[t], red[t][0]);
}

// ---------------- xpre = bn2(hid) + conv(xb); bn3 stats ----------------
__global__ void k_xpre_r9(const float* __restrict__ regb, const float* __restrict__ xb,
                          const void* __restrict__ convW, const void* __restrict__ convb,
                          const int* __restrict__ dflag,
                          const float* __restrict__ st2, float* __restrict__ st3,
                          float* __restrict__ xpre)
{
    int f = *dflag;
    int i = blockIdx.x*256 + threadIdx.x;
    float s[3] = {0,0,0}, q[3] = {0,0,0};
    if (i < TOT_X) {
        int b = i / 31788, r1 = i % 31788;
        int c = r1 / NL, r2 = r1 % NL;
        int n = r2 / 12, l = r2 % 12;
        float m2 = st2[c] * (1.0f/CNT_PER_C);
        float v2 = st2[3+c] * (1.0f/CNT_PER_C) - m2*m2;
        float hidv = (regb[((size_t)b*36 + c*12 + l)*NN + n] - m2) / sqrtf(v2 + 1e-5f);
        float cx = ldf(convb, c, f);
        #pragma unroll
        for (int cc = 0; cc < 3; cc++)
            cx += ldf(convW, c*3 + cc, f) * xb[((b*3 + cc)*NN + n)*12 + l];
        float v = hidv + cx;
        xpre[i] = v;
        s[c] = v; q[c] = v*v;
    }
    __shared__ float red[6][256];
    int t = threadIdx.x;
    #pragma unroll
    for (int j = 0; j < 3; j++) { red[j][t] = s[j]; red[3+j][t] = q[j]; }
    __syncthreads();
    for (int st_ = 128; st_ > 0; st_ >>= 1) {
        if (t < st_) {
            #pragma unroll
            for (int j = 0; j < 6; j++) red[j][t] += red[j][t+st_];
        }
        __syncthreads();
    }
    if (t < 6) atomicAdd(&st3[t], red[t][0]);
}

// ---------------- tail per (b,n): gather->d2v->softmax->pm->w->combined GLU ----------------
__global__ void __launch_bounds__(64)
k_tail_r9(const float* __restrict__ xpre, const float* __restrict__ st3,
          const float* __restrict__ phi, const float* __restrict__ topval,
          const int* __restrict__ topidx, const float* __restrict__ wc,
          const void* __restrict__ wie, const void* __restrict__ mixp,
          const int* __restrict__ dflag, float* __restrict__ out)
{
    int f = *dflag;
    int n = blockIdx.x, b = blockIdx.y, t = threadIdx.x;
    __shared__ float xe[3][10][12], mn[3][10], phis[24], ws[10];
    __shared__ float pm[3][10][12], pred[3][12];
    float m3[3], rs3[3];
    #pragma unroll
    for (int c = 0; c < 3; c++) {
        float m = st3[c] * (1.0f/CNT_PER_C);
        float v = st3[3+c] * (1.0f/CNT_PER_C) - m*m;
        m3[c] = m; rs3[c] = 1.0f / sqrtf(v + 1e-5f);
    }
    if (t < 24) phis[t] = phi[b*24 + t];
    if (t < 10) ws[t] = (t == 0 ? 1.0f : topval[n*9 + t - 1]) * ldf(wie, t, f);
    for (int i = t; i < 360; i += 64) {
        int c = i / 120, m = (i / 12) % 10, l = i % 12;
        int nn2 = (m == 0) ? n : topidx[n*9 + m - 1];
        xe[c][m][l] = (xpre[((size_t)(b*3 + c)*NN + nn2)*12 + l] - m3[c]) * rs3[c];
    }
    __syncthreads();
    if (t < 30) {
        int c = t / 10, m = t % 10;
        float s = 0.f;
        #pragma unroll
        for (int l = 0; l < 12; l++) s += xe[c][m][l];
        mn[c][m] = s * (1.0f/12.0f);
    }
    __syncthreads();
    float mix = ldf(mixp, 0, f);
    for (int pr = t; pr < 120; pr += 64) {
        int m = pr / 12, p = pr % 12;
        float y[3], sc[12], mx = -3.4e38f;
        #pragma unroll
        for (int c = 0; c < 3; c++) y[c] = phis[12+p] + mix*mn[c][m];
        #pragma unroll
        for (int l = 0; l < 12; l++) {
            float v = 0.f;
            #pragma unroll
            for (int c = 0; c < 3; c++) v += y[c] * (phis[l] + mix*mn[c][m]);
            sc[l] = v * (1.0f/36.0f); mx = fmaxf(mx, sc[l]);
        }
        float den = 0.f;
        #pragma unroll
        for (int l = 0; l < 12; l++) { float e = expf(sc[l] - mx); sc[l] = e; den += e; }
        float inv = 1.0f/den;
        float p0 = 0.f, p1 = 0.f, p2 = 0.f;
        #pragma unroll
        for (int l = 0; l < 12; l++) {
            float a = sc[l]*inv;
            p0 += a*xe[0][m][l]; p1 += a*xe[1][m][l]; p2 += a*xe[2][m][l];
        }
        pm[0][m][p] = p0; pm[1][m][p] = p1; pm[2][m][p] = p2;
    }
    __syncthreads();
    if (t < 36) {
        int c = t/12, p = t%12;
        float s = 0.f;
        #pragma unroll
        for (int m = 0; m < 10; m++) s += pm[c][m][p]*ws[m];
        pred[c][p] = s;
    }
    __syncthreads();
    if (t < 36) {
        int o = t/12, p = t%12;
        float o1 = wc[9+o]  + wc[o*3+0]*pred[0][p] + wc[o*3+1]*pred[1][p] + wc[o*3+2]*pred[2][p];
        float o2 = wc[21+o] + wc[12+o*3+0]*pred[0][p] + wc[12+o*3+1]*pred[1][p] + wc[12+o*3+2]*pred[2][p];
        out[((size_t)(b*3 + o)*NN + n)*12 + p] = o1 / (1.0f + expf(-o2));
    }
}

// ---------------------------------------------------------------------------
extern "C" void kernel_launch(void* const* d_in, const int* in_sizes, int n_in,
                              void* d_out, int out_size, void* d_ws, size_t ws_size,
                              hipStream_t stream)
{
    (void)in_sizes; (void)n_in;
    char* w = (char*)d_ws;
    auto alloc = [&](size_t bytes) { char* p = w; w += (bytes + 255) & ~(size_t)255; return p; };

    // fixed (~18.7 MB)
    float* xb     = (float*)alloc((size_t)TOT_X*4);
    float* regb   = (float*)alloc((size_t)TOT_X*4);
    float* xpre   = (float*)alloc((size_t)TOT_X*4);
    __hip_bfloat16* Whi1 = (__hip_bfloat16*)alloc(786432*2);
    __hip_bfloat16* Wlo1 = (__hip_bfloat16*)alloc(786432*2);
    __hip_bfloat16* Whi2 = (__hip_bfloat16*)alloc(786432*2);
    __hip_bfloat16* Wlo2 = (__hip_bfloat16*)alloc(786432*2);
    __hip_bfloat16* rhi  = (__hip_bfloat16*)alloc(18432*2);
    __hip_bfloat16* rlo  = (__hip_bfloat16*)alloc(18432*2);
    float* phi    = (float*)alloc(768*4);
    float* topval = (float*)alloc(7947*4);
    int*   topidx = (int*)alloc(7947*4);
    int*   tidx   = (int*)alloc(32*4);
    int*   didx   = (int*)alloc(32*4);
    float* stats  = (float*)alloc(18*4);  // bn1|bn2|bn3
    float* wc     = (float*)alloc(24*4);
    int*   dflag  = (int*)alloc(4);
    size_t fixedEnd = (size_t)(w - (char*)d_ws);

    const size_t XB = (size_t)NPAD*HH*2;                 // 917,504 B per act array per batch
    const size_t graphBytes = 452352*2 + 3118848 + 512;  // e1,e2,amat
    int CH = 0;
    for (int c = 32; c >= 1; c >>= 1) {
        size_t regBytes = 4*(size_t)c*XB;
        if (regBytes < graphBytes) regBytes = graphBytes;
        if (fixedEnd + regBytes + 4096 <= ws_size) { CH = c; break; }
    }
    if (CH == 0) {
        k_sent_r9<<<(out_size + 255)/256, 256, 0, stream>>>((float*)d_out, out_size);
        return;
    }
    char* regionB = w;
    float* e1   = (float*)regionB;
    float* e2   = (float*)(regionB + 452352);
    float* amat = (float*)(regionB + 904704);
    __hip_bfloat16* Xahi = (__hip_bfloat16*)regionB;
    __hip_bfloat16* Xalo = (__hip_bfloat16*)(regionB + (size_t)CH*XB);
    __hip_bfloat16* Xbhi = (__hip_bfloat16*)(regionB + 2*(size_t)CH*XB);
    __hip_bfloat16* Xblo = (__hip_bfloat16*)(regionB + 3*(size_t)CH*XB);

    hipMemsetAsync(stats, 0, 18*4, stream);

    k_probe_r9<<<1, 256, 0, stream>>>((const unsigned short*)d_in[0], dflag);
    k_prep_r9<<<1, 256, 0, stream>>>(d_in[2], d_in[3], d_in[19], d_in[20], d_in[21], d_in[22],
                                     d_in[25], d_in[26], d_in[27], d_in[28], d_in[29], d_in[30],
                                     dflag, tidx, didx, phi, wc);
    k_wsplit_r9<<<1024, 256, 0, stream>>>(d_in[13], dflag, 786432, Whi1, Wlo1);
    k_wsplit_r9<<<1024, 256, 0, stream>>>(d_in[15], dflag, 786432, Whi2, Wlo2);
    k_wsplit_r9<<<72,   256, 0, stream>>>(d_in[17], dflag, 18432, rhi, rlo);

    // graph phase (uses regionB as e1/e2/amat; completes before encoder reuses it)
    k_e_r9<<<883, 256, 0, stream>>>(d_in[4], d_in[5], d_in[6], dflag, e1, e2);
    k_amat_r9<<<3047, 256, 0, stream>>>(e1, e2, amat);
    k_rowsm_r9<<<883, 256, 0, stream>>>(amat);
    k_top9_r9<<<883, 256, 0, stream>>>(amat, topval, topidx);
    k_bn1_r9<<<512, 256, 0, stream>>>(d_in[0], dflag, stats);
    k_xb_r9<<<3974, 256, 0, stream>>>(d_in[0], dflag, stats, xb);

    for (int b0 = 0; b0 < BB; b0 += CH) {
        k_hid_r9<<<dim3(NN, CH), 256, 0, stream>>>(xb, d_in[4], d_in[7], d_in[8], d_in[9],
                                                   d_in[10], tidx, didx, dflag, b0, Xahi, Xalo);
        for (int i = 0; i < 3; i++) {
            k_gemm_r9<true, false, false><<<dim3(7, 4, CH), 256, 0, stream>>>(
                Whi1, Wlo1, (long)i*HH*HH, d_in[14], (long)i*HH, dflag,
                Xahi, Xalo, Xbhi, Xblo, (float*)nullptr, HH, b0);
            k_gemm_r9<false, true, false><<<dim3(7, 4, CH), 256, 0, stream>>>(
                Whi2, Wlo2, (long)i*HH*HH, d_in[16], (long)i*HH, dflag,
                Xbhi, Xblo, Xahi, Xalo, (float*)nullptr, HH, b0);
        }
        k_gemm_r9<false, false, true><<<dim3(7, 1, CH), 256, 0, stream>>>(
            rhi, rlo, 0, d_in[18], 0, dflag,
            Xahi, Xalo, (__hip_bfloat16*)nullptr, (__hip_bfloat16*)nullptr, regb, 36, b0);
    }

    k_bn2_r9<<<512, 256, 0, stream>>>(regb, stats + 6);
    k_xpre_r9<<<3974, 256, 0, stream>>>(regb, xb, d_in[11], d_in[12], dflag,
                                        stats + 6, stats + 12, xpre);
    k_tail_r9<<<dim3(NN, BB), 64, 0, stream>>>(xpre, stats + 12, phi, topval, topidx, wc,
                                               d_in[24], d_in[23], dflag, (float*)d_out);
}

// Round 10
// 975.245 us; speedup vs baseline: 87.3618x; 1.1061x over previous
//
#include <hip/hip_runtime.h>
#include <hip/hip_bf16.h>

// ---------------------------------------------------------------------------
// STD2Vformer forward, MI355X. Round 10 (R9 passed @1079us):
//  - gemm staging via __builtin_amdgcn_global_load_lds width=16 (m97 pattern),
//    LDS stride back to 32 shorts (wave-uniform base + lane*16 requirement)
//  - fused k_graph (amat row + standardize + softmax + top9) with transposed
//    e2t for coalesced, L2-resident row dots; amat/xb buffers eliminated
//  - k_hid: tsW in LDS (pad 37), 2ch/thread, packed 4B hi/lo stores
// ---------------------------------------------------------------------------

#define NN 883
#define NPAD 896
#define BB 32
#define HH 512
#define NL 10596            // N*L
#define CNT_PER_C 339072.0f // B*N*L
#define TOT_X 1017216       // B*C*N*L
#define LSTR 32             // LDS row stride in shorts (64B) - required by global_load_lds
#define LREG 4096           // shorts per LDS operand region (128*LSTR)

typedef __attribute__((ext_vector_type(8))) short bf16x8;
typedef __attribute__((ext_vector_type(4))) float f32x4;

static __device__ __forceinline__ float bf2f(__hip_bfloat16 v) { return __bfloat162float(v); }
static __device__ __forceinline__ float ldf(const void* p, long i, int f) {
    return f ? ((const float*)p)[i] : bf2f(((const __hip_bfloat16*)p)[i]);
}
static __device__ __forceinline__ unsigned short bfbits(float v) {
    __hip_bfloat16 h = __float2bfloat16(v);
    return *(unsigned short*)&h;
}
static __device__ __forceinline__ void async_copy16(const void* g, void* l) {
    __builtin_amdgcn_global_load_lds((const __attribute__((address_space(1))) void*)g,
                                     (__attribute__((address_space(3))) void*)l, 16, 0, 0);
}

struct alignas(8) BF4 { __hip_bfloat16 a, b, c, d; };

// ---------------- sentinel ----------------
__global__ void k_sent_r10(float* __restrict__ out, int n)
{
    int i = blockIdx.x*256 + threadIdx.x;
    if (i < n) out[i] = 1000.0f;
}

// ---------------- input dtype probe ----------------
__global__ void k_probe_r10(const unsigned short* __restrict__ u, int* __restrict__ flag)
{
    int t = threadIdx.x, cnt = 0;
    for (int i = t; i < 4096; i += 256) {
        int e = (u[i] >> 7) & 0xFF;
        cnt += (e >= 0xC0);
    }
    __shared__ int r[256];
    r[t] = cnt; __syncthreads();
    for (int s = 128; s > 0; s >>= 1) { if (t < s) r[t] += r[t+s]; __syncthreads(); }
    if (t == 0) *flag = (r[0] > 8) ? 1 : 0;
}

// ---------------- weight hi/lo split ----------------
__global__ void k_wsplit_r10(const void* __restrict__ src, const int* __restrict__ dflag,
                             int n, __hip_bfloat16* __restrict__ hi,
                             __hip_bfloat16* __restrict__ lo)
{
    int f = *dflag;
    for (int i = blockIdx.x*256 + threadIdx.x; i < n; i += gridDim.x*256) {
        float v = ldf(src, i, f);
        __hip_bfloat16 h = __float2bfloat16(v);
        hi[i] = h;
        lo[i] = __float2bfloat16(v - bf2f(h));
    }
}

// ---------------- prep: tidx, didx, phi(B,24), wc (combined GLU 3x3) ----------------
__global__ void k_prep_r10(const void* __restrict__ seqs, const void* __restrict__ tgts,
                           const void* __restrict__ w0, const void* __restrict__ b0,
                           const void* __restrict__ d2vW, const void* __restrict__ d2vb,
                           const void* __restrict__ fusW, const void* __restrict__ fusb,
                           const void* __restrict__ g1W, const void* __restrict__ g1b,
                           const void* __restrict__ g2W, const void* __restrict__ g2b,
                           const int* __restrict__ dflag,
                           int* __restrict__ tidx, int* __restrict__ didx,
                           float* __restrict__ phi, float* __restrict__ wc)
{
    int f = *dflag, t = threadIdx.x;
    if (t < 32) {
        int b = t;
        float h  = (ldf(seqs, (b*5+3)*12 + 11, f) + 0.5f) * 23.0f;
        float mi = (ldf(seqs, (b*5+4)*12 + 11, f) + 0.5f) * 59.0f;
        int ti = (int)((h * 60.0f + mi) / 5.0f);
        tidx[b] = ti < 0 ? 0 : (ti > 287 ? 287 : ti);
        int di = (int)((ldf(seqs, (b*5+2)*12 + 11, f) + 0.5f) * 6.0f);
        didx[b] = di < 0 ? 0 : (di > 6 ? 6 : di);
    }
    for (int i = t; i < 768; i += 256) {
        int b = i / 24, tt = i % 24;
        float tau[5];
        #pragma unroll
        for (int d = 0; d < 5; d++)
            tau[d] = (tt < 12) ? ldf(seqs, (b*5+d)*12 + tt, f)
                               : ldf(tgts, (b*5+d)*12 + tt - 12, f);
        float s = ldf(b0, 0, f);
        #pragma unroll
        for (int d = 0; d < 5; d++) s += tau[d] * ldf(w0, d, f);
        for (int k = 0; k < 16; k++) {
            float arg = ldf(d2vb, k, f);
            #pragma unroll
            for (int d = 0; d < 5; d++) arg += tau[d] * ldf(d2vW, k*5 + d, f);
            s += sinf(arg);
        }
        phi[i] = s;
    }
    if (t < 24) {
        if (t < 9) {
            int o = t / 3, c = t % 3; float s = 0.f;
            for (int d = 0; d < 128; d++) s += ldf(fusW, c*128+d, f) * ldf(g1W, d*3+o, f);
            wc[t] = s;
        } else if (t < 12) {
            int o = t - 9; float s = ldf(g1b, o, f);
            for (int d = 0; d < 128; d++) s += ldf(fusb, d, f) * ldf(g1W, d*3+o, f);
            wc[9 + o] = s;
        } else if (t < 21) {
            int j = t - 12; int o = j / 3, c = j % 3; float s = 0.f;
            for (int d = 0; d < 128; d++) s += ldf(fusW, c*128+d, f) * ldf(g2W, d*3+o, f);
            wc[12 + j] = s;
        } else {
            int o = t - 21; float s = ldf(g2b, o, f);
            for (int d = 0; d < 128; d++) s += ldf(fusb, d, f) * ldf(g2W, d*3+o, f);
            wc[21 + o] = s;
        }
    }
}

// ---------------- e1 (n-major) and e2t (d-major, transposed) ----------------
__global__ void k_e_r10(const void* __restrict__ mb, const void* __restrict__ We1,
                        const void* __restrict__ We2, const int* __restrict__ dflag,
                        float* __restrict__ e1, float* __restrict__ e2t)
{
    int f = *dflag;
    int idx = blockIdx.x*256 + threadIdx.x;       // 2*113024 exactly
    int which = idx >= 113024;
    int j = which ? idx - 113024 : idx;
    int d = j & 127, n = j >> 7;
    const void* W = which ? We2 : We1;
    float s = 0.f;
    for (int k = 0; k < 128; k++)
        s += ldf(mb, n*128 + k, f) * ldf(W, k*128 + d, f);
    if (which) e2t[d*NN + n] = s;
    else       e1[j] = s;
}

// ---- fused graph: row dot (coalesced e2t) + standardize + softmax + top9 ----
__global__ void __launch_bounds__(256)
k_graph_r10(const float* __restrict__ e1, const float* __restrict__ e2t,
            float* __restrict__ topval, int* __restrict__ topidx)
{
    int n = blockIdx.x, t = threadIdx.x;
    __shared__ float e1s[128];
    __shared__ float arow[NN];
    __shared__ float red[256];
    __shared__ int redi[256];
    if (t < 128) e1s[t] = e1[n*128 + t];
    __syncthreads();
    for (int m = t; m < NN; m += 256) {
        float acc = 0.f;
        #pragma unroll 8
        for (int k = 0; k < 128; k++) acc += e1s[k] * e2t[k*NN + m];
        arow[m] = acc;
    }
    __syncthreads();
    float s = 0.f;
    for (int m = t; m < NN; m += 256) s += arow[m];
    red[t] = s; __syncthreads();
    for (int st = 128; st > 0; st >>= 1) { if (t < st) red[t] += red[t+st]; __syncthreads(); }
    float mean = red[0] / 883.0f; __syncthreads();
    float ss = 0.f;
    for (int m = t; m < NN; m += 256) { float d = arow[m] - mean; ss += d*d; }
    red[t] = ss; __syncthreads();
    for (int st = 128; st > 0; st >>= 1) { if (t < st) red[t] += red[t+st]; __syncthreads(); }
    float rstd = 1.0f / sqrtf(red[0] / 882.0f); __syncthreads();
    for (int m = t; m < NN; m += 256) {
        float z = (arow[m] - mean) * rstd;
        z = fmaxf(z, 0.f);
        if (m == n) z -= 1e6f;
        arow[m] = z;
    }
    __syncthreads();
    float mx = -3.4e38f;
    for (int m = t; m < NN; m += 256) mx = fmaxf(mx, arow[m]);
    red[t] = mx; __syncthreads();
    for (int st = 128; st > 0; st >>= 1) { if (t < st) red[t] = fmaxf(red[t], red[t+st]); __syncthreads(); }
    float M = red[0]; __syncthreads();
    float ds = 0.f;
    for (int m = t; m < NN; m += 256) { float e = expf(arow[m] - M); arow[m] = e; ds += e; }
    red[t] = ds; __syncthreads();
    for (int st = 128; st > 0; st >>= 1) { if (t < st) red[t] += red[t+st]; __syncthreads(); }
    float inv = 1.0f / red[0]; __syncthreads();
    for (int m = t; m < NN; m += 256) arow[m] *= inv;
    __syncthreads();
    for (int j = 0; j < 9; j++) {
        float bv = -1.f; int bi = 0;
        for (int m = t; m < NN; m += 256) { float v = arow[m]; if (v > bv) { bv = v; bi = m; } }
        red[t] = bv; redi[t] = bi; __syncthreads();
        for (int st = 128; st > 0; st >>= 1) {
            if (t < st) {
                float ov = red[t+st]; int oi = redi[t+st];
                if (ov > red[t] || (ov == red[t] && oi < redi[t])) { red[t] = ov; redi[t] = oi; }
            }
            __syncthreads();
        }
        if (t == 0) {
            topval[n*9 + j] = red[0];
            topidx[n*9 + j] = redi[0];
            arow[redi[0]] = -1.f;
        }
        __syncthreads();
    }
}

// ---------------- bn1 stats ----------------
__global__ void k_bn1_r10(const void* __restrict__ x, const int* __restrict__ dflag,
                          float* __restrict__ st)
{
    int f = *dflag;
    float s[3] = {0,0,0}, q[3] = {0,0,0};
    for (int i = blockIdx.x*256 + threadIdx.x; i < TOT_X; i += 512*256) {
        int c = (i / NL) % 3;
        float v = ldf(x, i, f);
        s[c] += v; q[c] += v*v;
    }
    __shared__ float red[6][256];
    int t = threadIdx.x;
    #pragma unroll
    for (int j = 0; j < 3; j++) { red[j][t] = s[j]; red[3+j][t] = q[j]; }
    __syncthreads();
    for (int st_ = 128; st_ > 0; st_ >>= 1) {
        if (t < st_) {
            #pragma unroll
            for (int j = 0; j < 6; j++) red[j][t] += red[j][t+st_];
        }
        __syncthreads();
    }
    if (t < 6) atomicAdd(&st[t], red[t][0]);
}

// ---------------- build hidden (hi,lo) pairs; bn1 inline; tsW in LDS ----------------
__global__ void __launch_bounds__(256)
k_hid_r10(const void* __restrict__ in, const void* __restrict__ mb,
          const void* __restrict__ tide, const void* __restrict__ diwe,
          const void* __restrict__ tsW, const void* __restrict__ tsb,
          const int* __restrict__ tidx, const int* __restrict__ didx,
          const int* __restrict__ dflag, const float* __restrict__ st1,
          int b0, __hip_bfloat16* __restrict__ Xhi, __hip_bfloat16* __restrict__ Xlo)
{
    int f = *dflag;
    int n = blockIdx.x, bl = blockIdx.y, bg = b0 + bl, t = threadIdx.x;
    __shared__ float tsw[128*37];   // pad 37 to break bank aliasing
    __shared__ float tsbs[128];
    __shared__ float xbs[36];
    for (int i = t; i < 4608; i += 256) {
        int ch = i / 36, k = i % 36;
        tsw[ch*37 + k] = ldf(tsW, i, f);
    }
    if (t < 128) tsbs[t] = ldf(tsb, t, f);
    if (t < 36) {
        int c = t / 12, l = t % 12;
        float m = st1[c] * (1.0f/CNT_PER_C);
        float v = st1[3+c] * (1.0f/CNT_PER_C) - m*m;
        xbs[t] = (ldf(in, ((long)(bg*3 + c)*NN + n)*12 + l, f) - m) / sqrtf(v + 1e-5f);
    }
    __syncthreads();
    size_t base = ((size_t)bl*NPAD + n)*HH;
    float v[2];
    #pragma unroll
    for (int j = 0; j < 2; j++) {
        int ch = 2*t + j;
        if (ch < 128) {
            float a = tsbs[ch];
            #pragma unroll
            for (int k = 0; k < 36; k++) a += xbs[k] * tsw[ch*37 + k];
            v[j] = a;
        } else if (ch < 256) v[j] = ldf(mb, n*128 + ch - 128, f);
        else if (ch < 384)   v[j] = ldf(tide, tidx[bg]*128 + ch - 256, f);
        else                 v[j] = ldf(diwe, didx[bg]*128 + ch - 384, f);
    }
    unsigned short h0 = bfbits(v[0]), h1 = bfbits(v[1]);
    __hip_bfloat16 hb0, hb1;
    *(unsigned short*)&hb0 = h0; *(unsigned short*)&hb1 = h1;
    unsigned short l0 = bfbits(v[0] - bf2f(hb0)), l1 = bfbits(v[1] - bf2f(hb1));
    *(unsigned*)(Xhi + base + 2*t) = (unsigned)h0 | ((unsigned)h1 << 16);
    *(unsigned*)(Xlo + base + 2*t) = (unsigned)l0 | ((unsigned)l1 << 16);
}

// ---------------- MFMA GEMM: async global->LDS staging, hi/lo, 3 MFMAs/frag ----------------
template<bool RELU, bool RESID, bool F32OUT>
__global__ void __launch_bounds__(256)
k_gemm_r10(const __hip_bfloat16* __restrict__ Whi, const __hip_bfloat16* __restrict__ Wlo,
           long Woff, const void* __restrict__ bias, long boff,
           const int* __restrict__ dflag,
           const __hip_bfloat16* __restrict__ Xhi, const __hip_bfloat16* __restrict__ Xlo,
           __hip_bfloat16* __restrict__ Yhi, __hip_bfloat16* __restrict__ Ylo,
           float* __restrict__ outF, int HO, int b0)
{
    __shared__ __align__(16) short sm[4*LREG];   // Ahi|Alo|Bhi|Blo (32 KB)
    int tid = threadIdx.x, bz = blockIdx.z;
    int n0 = blockIdx.x * 128, ho0 = blockIdx.y * 128;
    int lane = tid & 63, wave = tid >> 6;
    int wm = wave & 1, wn = wave >> 1;
    int lm = lane & 15, quad = lane >> 4;

    f32x4 acc[4][4];
    #pragma unroll
    for (int i = 0; i < 4; i++)
        #pragma unroll
        for (int j = 0; j < 4; j++) acc[i][j] = (f32x4){0.f, 0.f, 0.f, 0.f};

    const size_t xb0 = (size_t)bz*NPAD*HH;
    // per-iteration row/col precompute (slot s = it*256+tid -> row=s>>2, kc=(s&3)*8)
    int rowi[2], kci[2], rri[2], nBi[2], lofsi[2];
    #pragma unroll
    for (int it = 0; it < 2; it++) {
        int s = it*256 + tid;
        rowi[it] = s >> 2; kci[it] = (s & 3) * 8;
        int rr = ho0 + rowi[it]; rri[it] = (rr >= HO) ? HO - 1 : rr;
        int nB = n0 + rowi[it]; nBi[it] = (nB >= NN) ? NN - 1 : nB;
        lofsi[it] = s * 8;   // shorts; byte = s*16 (wave-uniform base + lane*16)
    }

    for (int k0 = 0; k0 < 512; k0 += 32) {
        #pragma unroll
        for (int it = 0; it < 2; it++) {
            size_t wofs = (size_t)Woff + (size_t)rri[it]*512 + k0 + kci[it];
            size_t xofs = xb0 + (size_t)nBi[it]*HH + k0 + kci[it];
            int lofs = lofsi[it];
            async_copy16(Whi + wofs, &sm[lofs]);
            async_copy16(Wlo + wofs, &sm[LREG + lofs]);
            async_copy16(Xhi + xofs, &sm[2*LREG + lofs]);
            async_copy16(Xlo + xofs, &sm[3*LREG + lofs]);
        }
        __syncthreads();
        bf16x8 ah[4], al[4], bh[4], bl[4];
        #pragma unroll
        for (int mi = 0; mi < 4; mi++) {
            int o = (wm*64 + mi*16 + lm)*LSTR + quad*8;
            ah[mi] = *(const bf16x8*)&sm[o];
            al[mi] = *(const bf16x8*)&sm[LREG + o];
        }
        #pragma unroll
        for (int ni = 0; ni < 4; ni++) {
            int o = (wn*64 + ni*16 + lm)*LSTR + quad*8;
            bh[ni] = *(const bf16x8*)&sm[2*LREG + o];
            bl[ni] = *(const bf16x8*)&sm[3*LREG + o];
        }
        #pragma unroll
        for (int mi = 0; mi < 4; mi++)
            #pragma unroll
            for (int ni = 0; ni < 4; ni++) {
                acc[mi][ni] = __builtin_amdgcn_mfma_f32_16x16x32_bf16(ah[mi], bh[ni], acc[mi][ni], 0, 0, 0);
                acc[mi][ni] = __builtin_amdgcn_mfma_f32_16x16x32_bf16(ah[mi], bl[ni], acc[mi][ni], 0, 0, 0);
                acc[mi][ni] = __builtin_amdgcn_mfma_f32_16x16x32_bf16(al[mi], bh[ni], acc[mi][ni], 0, 0, 0);
            }
        __syncthreads();
    }

    int f = *dflag;
    // epilogue: C/D col(n)=lane&15, row(ho)=quad*4+r  [HW-verified R8]
    #pragma unroll
    for (int mi = 0; mi < 4; mi++) {
        int hor = ho0 + wm*64 + mi*16 + quad*4;
        float bv[4];
        #pragma unroll
        for (int r = 0; r < 4; r++) {
            int h = hor + r; if (h >= HO) h = HO - 1;
            bv[r] = ldf(bias, boff + h, f);
        }
        #pragma unroll
        for (int ni = 0; ni < 4; ni++) {
            int nc = n0 + wn*64 + ni*16 + lm;
            if (nc >= NN) continue;
            if constexpr (F32OUT) {
                #pragma unroll
                for (int r = 0; r < 4; r++) {
                    int h = hor + r;
                    if (h < HO) outF[((size_t)(b0 + bz)*HO + h)*NN + nc] = acc[mi][ni][r] + bv[r];
                }
            } else {
                size_t o = xb0 + (size_t)nc*HH + hor;
                float vals[4];
                #pragma unroll
                for (int r = 0; r < 4; r++) vals[r] = acc[mi][ni][r] + bv[r];
                if constexpr (RESID) {
                    BF4 rh = *(const BF4*)(Yhi + o);
                    BF4 rl = *(const BF4*)(Ylo + o);
                    vals[0] += bf2f(rh.a) + bf2f(rl.a);
                    vals[1] += bf2f(rh.b) + bf2f(rl.b);
                    vals[2] += bf2f(rh.c) + bf2f(rl.c);
                    vals[3] += bf2f(rh.d) + bf2f(rl.d);
                }
                if constexpr (RELU) {
                    #pragma unroll
                    for (int r = 0; r < 4; r++) vals[r] = fmaxf(vals[r], 0.f);
                }
                BF4 hi, lo;
                hi.a = __float2bfloat16(vals[0]); lo.a = __float2bfloat16(vals[0] - bf2f(hi.a));
                hi.b = __float2bfloat16(vals[1]); lo.b = __float2bfloat16(vals[1] - bf2f(hi.b));
                hi.c = __float2bfloat16(vals[2]); lo.c = __float2bfloat16(vals[2] - bf2f(hi.c));
                hi.d = __float2bfloat16(vals[3]); lo.d = __float2bfloat16(vals[3] - bf2f(hi.d));
                *(BF4*)(Yhi + o) = hi;
                *(BF4*)(Ylo + o) = lo;
            }
        }
    }
}

// ---------------- bn2 stats over reg (B,36,N) ----------------
__global__ void k_bn2_r10(const float* __restrict__ x, float* __restrict__ st)
{
    float s[3] = {0,0,0}, q[3] = {0,0,0};
    for (int i = blockIdx.x*256 + threadIdx.x; i < TOT_X; i += 512*256) {
        int c = ((i / NN) % 36) / 12;
        float v = x[i];
        s[c] += v; q[c] += v*v;
    }
    __shared__ float red[6][256];
    int t = threadIdx.x;
    #pragma unroll
    for (int j = 0; j < 3; j++) { red[j][t] = s[j]; red[3+j][t] = q[j]; }
    __syncthreads();
    for (int st_ = 128; st_ > 0; st_ >>= 1) {
        if (t < st_) {
            #pragma unroll
            for (int j = 0; j < 6; j++) red[j][t] += red[j][t+st_];
        }
        __syncthreads();
    }
    if (t < 6) atomicAdd(&st[t], red[t][0]);
}

// ---------------- xpre = bn2(reg) + conv(bn1(in)); bn3 stats ----------------
__global__ void k_xpre_r10(const float* __restrict__ regb, const void* __restrict__ in,
                           const void* __restrict__ convW, const void* __restrict__ convb,
                           const int* __restrict__ dflag, const float* __restrict__ st1,
                           const float* __restrict__ st2, float* __restrict__ st3,
                           float* __restrict__ xpre)
{
    int f = *dflag;
    int i = blockIdx.x*256 + threadIdx.x;
    float s[3] = {0,0,0}, q[3] = {0,0,0};
    if (i < TOT_X) {
        int b = i / 31788, r1 = i % 31788;
        int c = r1 / NL, r2 = r1 % NL;
        int n = r2 / 12, l = r2 % 12;
        float m2 = st2[c] * (1.0f/CNT_PER_C);
        float v2 = st2[3+c] * (1.0f/CNT_PER_C) - m2*m2;
        float hidv = (regb[((size_t)b*36 + c*12 + l)*NN + n] - m2) / sqrtf(v2 + 1e-5f);
        float cx = ldf(convb, c, f);
        #pragma unroll
        for (int cc = 0; cc < 3; cc++) {
            float m1 = st1[cc] * (1.0f/CNT_PER_C);
            float v1 = st1[3+cc] * (1.0f/CNT_PER_C) - m1*m1;
            float xbv = (ldf(in, ((long)(b*3 + cc)*NN + n)*12 + l, f) - m1) / sqrtf(v1 + 1e-5f);
            cx += ldf(convW, c*3 + cc, f) * xbv;
        }
        float v = hidv + cx;
        xpre[i] = v;
        s[c] = v; q[c] = v*v;
    }
    __shared__ float red[6][256];
    int t = threadIdx.x;
    #pragma unroll
    for (int j = 0; j < 3; j++) { red[j][t] = s[j]; red[3+j][t] = q[j]; }
    __syncthreads();
    for (int st_ = 128; st_ > 0; st_ >>= 1) {
        if (t < st_) {
            #pragma unroll
            for (int j = 0; j < 6; j++) red[j][t] += red[j][t+st_];
        }
        __syncthreads();
    }
    if (t < 6) atomicAdd(&st3[t], red[t][0]);
}

// ---------------- tail per (b,n) ----------------
__global__ void __launch_bounds__(64)
k_tail_r10(const float* __restrict__ xpre, const float* __restrict__ st3,
           const float* __restrict__ phi, const float* __restrict__ topval,
           const int* __restrict__ topidx, const float* __restrict__ wc,
           const void* __restrict__ wie, const void* __restrict__ mixp,
           const int* __restrict__ dflag, float* __restrict__ out)
{
    int f = *dflag;
    int n = blockIdx.x, b = blockIdx.y, t = threadIdx.x;
    __shared__ float xe[3][10][12], mn[3][10], phis[24], ws[10];
    __shared__ float pm[3][10][12], pred[3][12];
    float m3[3], rs3[3];
    #pragma unroll
    for (int c = 0; c < 3; c++) {
        float m = st3[c] * (1.0f/CNT_PER_C);
        float v = st3[3+c] * (1.0f/CNT_PER_C) - m*m;
        m3[c] = m; rs3[c] = 1.0f / sqrtf(v + 1e-5f);
    }
    if (t < 24) phis[t] = phi[b*24 + t];
    if (t < 10) ws[t] = (t == 0 ? 1.0f : topval[n*9 + t - 1]) * ldf(wie, t, f);
    for (int i = t; i < 360; i += 64) {
        int c = i / 120, m = (i / 12) % 10, l = i % 12;
        int nn2 = (m == 0) ? n : topidx[n*9 + m - 1];
        xe[c][m][l] = (xpre[((size_t)(b*3 + c)*NN + nn2)*12 + l] - m3[c]) * rs3[c];
    }
    __syncthreads();
    if (t < 30) {
        int c = t / 10, m = t % 10;
        float s = 0.f;
        #pragma unroll
        for (int l = 0; l < 12; l++) s += xe[c][m][l];
        mn[c][m] = s * (1.0f/12.0f);
    }
    __syncthreads();
    float mix = ldf(mixp, 0, f);
    for (int pr = t; pr < 120; pr += 64) {
        int m = pr / 12, p = pr % 12;
        float y[3], sc[12], mx = -3.4e38f;
        #pragma unroll
        for (int c = 0; c < 3; c++) y[c] = phis[12+p] + mix*mn[c][m];
        #pragma unroll
        for (int l = 0; l < 12; l++) {
            float v = 0.f;
            #pragma unroll
            for (int c = 0; c < 3; c++) v += y[c] * (phis[l] + mix*mn[c][m]);
            sc[l] = v * (1.0f/36.0f); mx = fmaxf(mx, sc[l]);
        }
        float den = 0.f;
        #pragma unroll
        for (int l = 0; l < 12; l++) { float e = expf(sc[l] - mx); sc[l] = e; den += e; }
        float inv = 1.0f/den;
        float p0 = 0.f, p1 = 0.f, p2 = 0.f;
        #pragma unroll
        for (int l = 0; l < 12; l++) {
            float a = sc[l]*inv;
            p0 += a*xe[0][m][l]; p1 += a*xe[1][m][l]; p2 += a*xe[2][m][l];
        }
        pm[0][m][p] = p0; pm[1][m][p] = p1; pm[2][m][p] = p2;
    }
    __syncthreads();
    if (t < 36) {
        int c = t/12, p = t%12;
        float s = 0.f;
        #pragma unroll
        for (int m = 0; m < 10; m++) s += pm[c][m][p]*ws[m];
        pred[c][p] = s;
    }
    __syncthreads();
    if (t < 36) {
        int o = t/12, p = t%12;
        float o1 = wc[9+o]  + wc[o*3+0]*pred[0][p] + wc[o*3+1]*pred[1][p] + wc[o*3+2]*pred[2][p];
        float o2 = wc[21+o] + wc[12+o*3+0]*pred[0][p] + wc[12+o*3+1]*pred[1][p] + wc[12+o*3+2]*pred[2][p];
        out[((size_t)(b*3 + o)*NN + n)*12 + p] = o1 / (1.0f + expf(-o2));
    }
}

// ---------------------------------------------------------------------------
extern "C" void kernel_launch(void* const* d_in, const int* in_sizes, int n_in,
                              void* d_out, int out_size, void* d_ws, size_t ws_size,
                              hipStream_t stream)
{
    (void)in_sizes; (void)n_in;
    char* w = (char*)d_ws;
    auto alloc = [&](size_t bytes) { char* p = w; w += (bytes + 255) & ~(size_t)255; return p; };

    // fixed (~15.4 MB)
    float* regb   = (float*)alloc((size_t)TOT_X*4);
    float* xpre   = (float*)alloc((size_t)TOT_X*4);
    __hip_bfloat16* Whi1 = (__hip_bfloat16*)alloc(786432*2);
    __hip_bfloat16* Wlo1 = (__hip_bfloat16*)alloc(786432*2);
    __hip_bfloat16* Whi2 = (__hip_bfloat16*)alloc(786432*2);
    __hip_bfloat16* Wlo2 = (__hip_bfloat16*)alloc(786432*2);
    __hip_bfloat16* rhi  = (__hip_bfloat16*)alloc(18432*2);
    __hip_bfloat16* rlo  = (__hip_bfloat16*)alloc(18432*2);
    float* e1     = (float*)alloc(113024*4);
    float* e2t    = (float*)alloc(113024*4);
    float* phi    = (float*)alloc(768*4);
    float* topval = (float*)alloc(7947*4);
    int*   topidx = (int*)alloc(7947*4);
    int*   tidx   = (int*)alloc(32*4);
    int*   didx   = (int*)alloc(32*4);
    float* stats  = (float*)alloc(18*4);  // bn1|bn2|bn3
    float* wc     = (float*)alloc(24*4);
    int*   dflag  = (int*)alloc(4);
    size_t fixedEnd = (size_t)(w - (char*)d_ws);

    const size_t XB = (size_t)NPAD*HH*2;                 // bytes per act array per batch elem
    int CH = 0;
    for (int c = 32; c >= 1; c >>= 1) {
        if (fixedEnd + 4*(size_t)c*XB + 4096 <= ws_size) { CH = c; break; }
    }
    if (CH == 0) {
        k_sent_r10<<<(out_size + 255)/256, 256, 0, stream>>>((float*)d_out, out_size);
        return;
    }
    char* regionB = w;
    __hip_bfloat16* Xahi = (__hip_bfloat16*)regionB;
    __hip_bfloat16* Xalo = (__hip_bfloat16*)(regionB + (size_t)CH*XB);
    __hip_bfloat16* Xbhi = (__hip_bfloat16*)(regionB + 2*(size_t)CH*XB);
    __hip_bfloat16* Xblo = (__hip_bfloat16*)(regionB + 3*(size_t)CH*XB);

    hipMemsetAsync(stats, 0, 18*4, stream);

    k_probe_r10<<<1, 256, 0, stream>>>((const unsigned short*)d_in[0], dflag);
    k_prep_r10<<<1, 256, 0, stream>>>(d_in[2], d_in[3], d_in[19], d_in[20], d_in[21], d_in[22],
                                      d_in[25], d_in[26], d_in[27], d_in[28], d_in[29], d_in[30],
                                      dflag, tidx, didx, phi, wc);
    k_wsplit_r10<<<1024, 256, 0, stream>>>(d_in[13], dflag, 786432, Whi1, Wlo1);
    k_wsplit_r10<<<1024, 256, 0, stream>>>(d_in[15], dflag, 786432, Whi2, Wlo2);
    k_wsplit_r10<<<72,   256, 0, stream>>>(d_in[17], dflag, 18432, rhi, rlo);

    k_e_r10<<<883, 256, 0, stream>>>(d_in[4], d_in[5], d_in[6], dflag, e1, e2t);
    k_graph_r10<<<883, 256, 0, stream>>>(e1, e2t, topval, topidx);
    k_bn1_r10<<<512, 256, 0, stream>>>(d_in[0], dflag, stats);

    for (int b0 = 0; b0 < BB; b0 += CH) {
        k_hid_r10<<<dim3(NN, CH), 256, 0, stream>>>(d_in[0], d_in[4], d_in[7], d_in[8],
                                                    d_in[9], d_in[10], tidx, didx, dflag,
                                                    stats, b0, Xahi, Xalo);
        for (int i = 0; i < 3; i++) {
            k_gemm_r10<true, false, false><<<dim3(7, 4, CH), 256, 0, stream>>>(
                Whi1, Wlo1, (long)i*HH*HH, d_in[14], (long)i*HH, dflag,
                Xahi, Xalo, Xbhi, Xblo, (float*)nullptr, HH, b0);
            k_gemm_r10<false, true, false><<<dim3(7, 4, CH), 256, 0, stream>>>(
                Whi2, Wlo2, (long)i*HH*HH, d_in[16], (long)i*HH, dflag,
                Xbhi, Xblo, Xahi, Xalo, (float*)nullptr, HH, b0);
        }
        k_gemm_r10<false, false, true><<<dim3(7, 1, CH), 256, 0, stream>>>(
            rhi, rlo, 0, d_in[18], 0, dflag,
            Xahi, Xalo, (__hip_bfloat16*)nullptr, (__hip_bfloat16*)nullptr, regb, 36, b0);
    }

    k_bn2_r10<<<512, 256, 0, stream>>>(regb, stats + 6);
    k_xpre_r10<<<3974, 256, 0, stream>>>(regb, d_in[0], d_in[11], d_in[12], dflag,
                                         stats, stats + 6, stats + 12, xpre);
    k_tail_r10<<<dim3(NN, BB), 64, 0, stream>>>(xpre, stats + 12, phi, topval, topidx, wc,
                                                d_in[24], d_in[23], dflag, (float*)d_out);
}

// Round 11
// 918.792 us; speedup vs baseline: 92.7295x; 1.0614x over previous
//
#include <hip/hip_runtime.h>
#include <hip/hip_bf16.h>

// ---------------------------------------------------------------------------
// STD2Vformer forward, MI355X. Round 11 (R10 passed @975us):
//  - reg gemm writes regT (b,N,36) + fused bn2 stats in epilogue (k_bn2 gone)
//    -> k_xpre reads coalesced-ish (was 3.5KB-stride, 92us @173GB/s)
//  - k_hid: 8 nodes/block, tsW staged once per 8 n (8x less L2 refetch)
//  - gemms unchanged (m97-plateau ~880 TF effective; known local ceiling)
// ---------------------------------------------------------------------------

#define NN 883
#define NPAD 896
#define BB 32
#define HH 512
#define NL 10596            // N*L
#define CNT_PER_C 339072.0f // B*N*L
#define TOT_X 1017216       // B*C*N*L
#define LSTR 32             // LDS row stride in shorts (64B) - global_load_lds layout
#define LREG 4096           // shorts per LDS operand region (128*LSTR)

typedef __attribute__((ext_vector_type(8))) short bf16x8;
typedef __attribute__((ext_vector_type(4))) float f32x4;

static __device__ __forceinline__ float bf2f(__hip_bfloat16 v) { return __bfloat162float(v); }
static __device__ __forceinline__ float ldf(const void* p, long i, int f) {
    return f ? ((const float*)p)[i] : bf2f(((const __hip_bfloat16*)p)[i]);
}
static __device__ __forceinline__ unsigned short bfbits(float v) {
    __hip_bfloat16 h = __float2bfloat16(v);
    return *(unsigned short*)&h;
}
static __device__ __forceinline__ void async_copy16(const void* g, void* l) {
    __builtin_amdgcn_global_load_lds((const __attribute__((address_space(1))) void*)g,
                                     (__attribute__((address_space(3))) void*)l, 16, 0, 0);
}

struct alignas(8) BF4 { __hip_bfloat16 a, b, c, d; };

// ---------------- sentinel ----------------
__global__ void k_sent_r11(float* __restrict__ out, int n)
{
    int i = blockIdx.x*256 + threadIdx.x;
    if (i < n) out[i] = 1000.0f;
}

// ---------------- input dtype probe ----------------
__global__ void k_probe_r11(const unsigned short* __restrict__ u, int* __restrict__ flag)
{
    int t = threadIdx.x, cnt = 0;
    for (int i = t; i < 4096; i += 256) {
        int e = (u[i] >> 7) & 0xFF;
        cnt += (e >= 0xC0);
    }
    __shared__ int r[256];
    r[t] = cnt; __syncthreads();
    for (int s = 128; s > 0; s >>= 1) { if (t < s) r[t] += r[t+s]; __syncthreads(); }
    if (t == 0) *flag = (r[0] > 8) ? 1 : 0;
}

// ---------------- weight hi/lo split ----------------
__global__ void k_wsplit_r11(const void* __restrict__ src, const int* __restrict__ dflag,
                             int n, __hip_bfloat16* __restrict__ hi,
                             __hip_bfloat16* __restrict__ lo)
{
    int f = *dflag;
    for (int i = blockIdx.x*256 + threadIdx.x; i < n; i += gridDim.x*256) {
        float v = ldf(src, i, f);
        __hip_bfloat16 h = __float2bfloat16(v);
        hi[i] = h;
        lo[i] = __float2bfloat16(v - bf2f(h));
    }
}

// ---------------- prep: tidx, didx, phi(B,24), wc (combined GLU 3x3) ----------------
__global__ void k_prep_r11(const void* __restrict__ seqs, const void* __restrict__ tgts,
                           const void* __restrict__ w0, const void* __restrict__ b0,
                           const void* __restrict__ d2vW, const void* __restrict__ d2vb,
                           const void* __restrict__ fusW, const void* __restrict__ fusb,
                           const void* __restrict__ g1W, const void* __restrict__ g1b,
                           const void* __restrict__ g2W, const void* __restrict__ g2b,
                           const int* __restrict__ dflag,
                           int* __restrict__ tidx, int* __restrict__ didx,
                           float* __restrict__ phi, float* __restrict__ wc)
{
    int f = *dflag, t = threadIdx.x;
    if (t < 32) {
        int b = t;
        float h  = (ldf(seqs, (b*5+3)*12 + 11, f) + 0.5f) * 23.0f;
        float mi = (ldf(seqs, (b*5+4)*12 + 11, f) + 0.5f) * 59.0f;
        int ti = (int)((h * 60.0f + mi) / 5.0f);
        tidx[b] = ti < 0 ? 0 : (ti > 287 ? 287 : ti);
        int di = (int)((ldf(seqs, (b*5+2)*12 + 11, f) + 0.5f) * 6.0f);
        didx[b] = di < 0 ? 0 : (di > 6 ? 6 : di);
    }
    for (int i = t; i < 768; i += 256) {
        int b = i / 24, tt = i % 24;
        float tau[5];
        #pragma unroll
        for (int d = 0; d < 5; d++)
            tau[d] = (tt < 12) ? ldf(seqs, (b*5+d)*12 + tt, f)
                               : ldf(tgts, (b*5+d)*12 + tt - 12, f);
        float s = ldf(b0, 0, f);
        #pragma unroll
        for (int d = 0; d < 5; d++) s += tau[d] * ldf(w0, d, f);
        for (int k = 0; k < 16; k++) {
            float arg = ldf(d2vb, k, f);
            #pragma unroll
            for (int d = 0; d < 5; d++) arg += tau[d] * ldf(d2vW, k*5 + d, f);
            s += sinf(arg);
        }
        phi[i] = s;
    }
    if (t < 24) {
        if (t < 9) {
            int o = t / 3, c = t % 3; float s = 0.f;
            for (int d = 0; d < 128; d++) s += ldf(fusW, c*128+d, f) * ldf(g1W, d*3+o, f);
            wc[t] = s;
        } else if (t < 12) {
            int o = t - 9; float s = ldf(g1b, o, f);
            for (int d = 0; d < 128; d++) s += ldf(fusb, d, f) * ldf(g1W, d*3+o, f);
            wc[9 + o] = s;
        } else if (t < 21) {
            int j = t - 12; int o = j / 3, c = j % 3; float s = 0.f;
            for (int d = 0; d < 128; d++) s += ldf(fusW, c*128+d, f) * ldf(g2W, d*3+o, f);
            wc[12 + j] = s;
        } else {
            int o = t - 21; float s = ldf(g2b, o, f);
            for (int d = 0; d < 128; d++) s += ldf(fusb, d, f) * ldf(g2W, d*3+o, f);
            wc[21 + o] = s;
        }
    }
}

// ---------------- e1 (n-major) and e2t (d-major, transposed) ----------------
__global__ void k_e_r11(const void* __restrict__ mb, const void* __restrict__ We1,
                        const void* __restrict__ We2, const int* __restrict__ dflag,
                        float* __restrict__ e1, float* __restrict__ e2t)
{
    int f = *dflag;
    int idx = blockIdx.x*256 + threadIdx.x;       // 2*113024 exactly
    int which = idx >= 113024;
    int j = which ? idx - 113024 : idx;
    int d = j & 127, n = j >> 7;
    const void* W = which ? We2 : We1;
    float s = 0.f;
    for (int k = 0; k < 128; k++)
        s += ldf(mb, n*128 + k, f) * ldf(W, k*128 + d, f);
    if (which) e2t[d*NN + n] = s;
    else       e1[j] = s;
}

// ---- fused graph: row dot (coalesced e2t) + standardize + softmax + top9 ----
__global__ void __launch_bounds__(256)
k_graph_r11(const float* __restrict__ e1, const float* __restrict__ e2t,
            float* __restrict__ topval, int* __restrict__ topidx)
{
    int n = blockIdx.x, t = threadIdx.x;
    __shared__ float e1s[128];
    __shared__ float arow[NN];
    __shared__ float red[256];
    __shared__ int redi[256];
    if (t < 128) e1s[t] = e1[n*128 + t];
    __syncthreads();
    for (int m = t; m < NN; m += 256) {
        float acc = 0.f;
        #pragma unroll 8
        for (int k = 0; k < 128; k++) acc += e1s[k] * e2t[k*NN + m];
        arow[m] = acc;
    }
    __syncthreads();
    float s = 0.f;
    for (int m = t; m < NN; m += 256) s += arow[m];
    red[t] = s; __syncthreads();
    for (int st = 128; st > 0; st >>= 1) { if (t < st) red[t] += red[t+st]; __syncthreads(); }
    float mean = red[0] / 883.0f; __syncthreads();
    float ss = 0.f;
    for (int m = t; m < NN; m += 256) { float d = arow[m] - mean; ss += d*d; }
    red[t] = ss; __syncthreads();
    for (int st = 128; st > 0; st >>= 1) { if (t < st) red[t] += red[t+st]; __syncthreads(); }
    float rstd = 1.0f / sqrtf(red[0] / 882.0f); __syncthreads();
    for (int m = t; m < NN; m += 256) {
        float z = (arow[m] - mean) * rstd;
        z = fmaxf(z, 0.f);
        if (m == n) z -= 1e6f;
        arow[m] = z;
    }
    __syncthreads();
    float mx = -3.4e38f;
    for (int m = t; m < NN; m += 256) mx = fmaxf(mx, arow[m]);
    red[t] = mx; __syncthreads();
    for (int st = 128; st > 0; st >>= 1) { if (t < st) red[t] = fmaxf(red[t], red[t+st]); __syncthreads(); }
    float M = red[0]; __syncthreads();
    float ds = 0.f;
    for (int m = t; m < NN; m += 256) { float e = expf(arow[m] - M); arow[m] = e; ds += e; }
    red[t] = ds; __syncthreads();
    for (int st = 128; st > 0; st >>= 1) { if (t < st) red[t] += red[t+st]; __syncthreads(); }
    float inv = 1.0f / red[0]; __syncthreads();
    for (int m = t; m < NN; m += 256) arow[m] *= inv;
    __syncthreads();
    for (int j = 0; j < 9; j++) {
        float bv = -1.f; int bi = 0;
        for (int m = t; m < NN; m += 256) { float v = arow[m]; if (v > bv) { bv = v; bi = m; } }
        red[t] = bv; redi[t] = bi; __syncthreads();
        for (int st = 128; st > 0; st >>= 1) {
            if (t < st) {
                float ov = red[t+st]; int oi = redi[t+st];
                if (ov > red[t] || (ov == red[t] && oi < redi[t])) { red[t] = ov; redi[t] = oi; }
            }
            __syncthreads();
        }
        if (t == 0) {
            topval[n*9 + j] = red[0];
            topidx[n*9 + j] = redi[0];
            arow[redi[0]] = -1.f;
        }
        __syncthreads();
    }
}

// ---------------- bn1 stats ----------------
__global__ void k_bn1_r11(const void* __restrict__ x, const int* __restrict__ dflag,
                          float* __restrict__ st)
{
    int f = *dflag;
    float s[3] = {0,0,0}, q[3] = {0,0,0};
    for (int i = blockIdx.x*256 + threadIdx.x; i < TOT_X; i += 512*256) {
        int c = (i / NL) % 3;
        float v = ldf(x, i, f);
        s[c] += v; q[c] += v*v;
    }
    __shared__ float red[6][256];
    int t = threadIdx.x;
    #pragma unroll
    for (int j = 0; j < 3; j++) { red[j][t] = s[j]; red[3+j][t] = q[j]; }
    __syncthreads();
    for (int st_ = 128; st_ > 0; st_ >>= 1) {
        if (t < st_) {
            #pragma unroll
            for (int j = 0; j < 6; j++) red[j][t] += red[j][t+st_];
        }
        __syncthreads();
    }
    if (t < 6) atomicAdd(&st[t], red[t][0]);
}

// ---------------- build hidden (hi,lo); 8 nodes/block; bn1 inline ----------------
__global__ void __launch_bounds__(256)
k_hid_r11(const void* __restrict__ in, const void* __restrict__ mb,
          const void* __restrict__ tide, const void* __restrict__ diwe,
          const void* __restrict__ tsW, const void* __restrict__ tsb,
          const int* __restrict__ tidx, const int* __restrict__ didx,
          const int* __restrict__ dflag, const float* __restrict__ st1,
          int b0, __hip_bfloat16* __restrict__ Xhi, __hip_bfloat16* __restrict__ Xlo)
{
    int f = *dflag;
    int bl = blockIdx.y, bg = b0 + bl, t = threadIdx.x;
    int n0 = blockIdx.x * 8;
    __shared__ float tsw[128*37];
    __shared__ float tsbs[128];
    __shared__ float xbs[8][36];
    float m1[3], r1v[3];
    #pragma unroll
    for (int c = 0; c < 3; c++) {
        float m = st1[c] * (1.0f/CNT_PER_C);
        float v = st1[3+c] * (1.0f/CNT_PER_C) - m*m;
        m1[c] = m; r1v[c] = 1.0f / sqrtf(v + 1e-5f);
    }
    for (int i = t; i < 4608; i += 256)
        tsw[(i/36)*37 + (i%36)] = ldf(tsW, i, f);
    if (t < 128) tsbs[t] = ldf(tsb, t, f);
    for (int i = t; i < 288; i += 256) {
        int nl = i / 36, k = i % 36;
        int c = k / 12, l = k % 12;
        int n = n0 + nl; if (n >= NN) n = NN - 1;
        xbs[nl][k] = (ldf(in, ((long)(bg*3 + c)*NN + n)*12 + l, f) - m1[c]) * r1v[c];
    }
    __syncthreads();
    int nloc = t >> 5, lane = t & 31;
    int n = n0 + nloc;
    if (n >= NN) return;
    size_t base = ((size_t)bl*NPAD + n)*HH;
    const float* xr = xbs[nloc];
    #pragma unroll
    for (int j = 0; j < 8; j++) {
        int ch0 = j*64 + lane*2;
        float v0, v1;
        if (j < 2) {
            float a0 = tsbs[ch0], a1 = tsbs[ch0+1];
            #pragma unroll
            for (int k = 0; k < 36; k++) {
                float xv = xr[k];
                a0 += xv * tsw[ch0*37 + k];
                a1 += xv * tsw[(ch0+1)*37 + k];
            }
            v0 = a0; v1 = a1;
        } else if (j < 4) {
            v0 = ldf(mb, n*128 + ch0 - 128, f);
            v1 = ldf(mb, n*128 + ch0 - 127, f);
        } else if (j < 6) {
            v0 = ldf(tide, tidx[bg]*128 + ch0 - 256, f);
            v1 = ldf(tide, tidx[bg]*128 + ch0 - 255, f);
        } else {
            v0 = ldf(diwe, didx[bg]*128 + ch0 - 384, f);
            v1 = ldf(diwe, didx[bg]*128 + ch0 - 383, f);
        }
        unsigned short h0 = bfbits(v0), h1 = bfbits(v1);
        __hip_bfloat16 hb0, hb1;
        *(unsigned short*)&hb0 = h0; *(unsigned short*)&hb1 = h1;
        unsigned short l0 = bfbits(v0 - bf2f(hb0)), l1 = bfbits(v1 - bf2f(hb1));
        *(unsigned*)(Xhi + base + ch0) = (unsigned)h0 | ((unsigned)h1 << 16);
        *(unsigned*)(Xlo + base + ch0) = (unsigned)l0 | ((unsigned)l1 << 16);
    }
}

// ---------------- MFMA GEMM: async staging, hi/lo, 3 MFMAs/frag ----------------
// REGT mode: write regT (b,N,36) float4 + fused bn2 stats (block reduce + atomicAdd)
template<bool RELU, bool RESID, bool REGT>
__global__ void __launch_bounds__(256)
k_gemm_r11(const __hip_bfloat16* __restrict__ Whi, const __hip_bfloat16* __restrict__ Wlo,
           long Woff, const void* __restrict__ bias, long boff,
           const int* __restrict__ dflag,
           const __hip_bfloat16* __restrict__ Xhi, const __hip_bfloat16* __restrict__ Xlo,
           __hip_bfloat16* __restrict__ Yhi, __hip_bfloat16* __restrict__ Ylo,
           float* __restrict__ regT, float* __restrict__ st2, int HO, int b0)
{
    __shared__ __align__(16) short sm[4*LREG];   // Ahi|Alo|Bhi|Blo (32 KB)
    int tid = threadIdx.x, bz = blockIdx.z;
    int n0 = blockIdx.x * 128, ho0 = blockIdx.y * 128;
    int lane = tid & 63, wave = tid >> 6;
    int wm = wave & 1, wn = wave >> 1;
    int lm = lane & 15, quad = lane >> 4;

    f32x4 acc[4][4];
    #pragma unroll
    for (int i = 0; i < 4; i++)
        #pragma unroll
        for (int j = 0; j < 4; j++) acc[i][j] = (f32x4){0.f, 0.f, 0.f, 0.f};

    const size_t xb0 = (size_t)bz*NPAD*HH;
    int rri[2], nBi[2], kci[2], lofsi[2];
    #pragma unroll
    for (int it = 0; it < 2; it++) {
        int s = it*256 + tid;
        int row = s >> 2; kci[it] = (s & 3) * 8;
        int rr = ho0 + row; rri[it] = (rr >= HO) ? HO - 1 : rr;
        int nB = n0 + row; nBi[it] = (nB >= NN) ? NN - 1 : nB;
        lofsi[it] = s * 8;
    }

    for (int k0 = 0; k0 < 512; k0 += 32) {
        #pragma unroll
        for (int it = 0; it < 2; it++) {
            size_t wofs = (size_t)Woff + (size_t)rri[it]*512 + k0 + kci[it];
            size_t xofs = xb0 + (size_t)nBi[it]*HH + k0 + kci[it];
            int lofs = lofsi[it];
            async_copy16(Whi + wofs, &sm[lofs]);
            async_copy16(Wlo + wofs, &sm[LREG + lofs]);
            async_copy16(Xhi + xofs, &sm[2*LREG + lofs]);
            async_copy16(Xlo + xofs, &sm[3*LREG + lofs]);
        }
        __syncthreads();
        bf16x8 ah[4], al[4], bh[4], bl[4];
        #pragma unroll
        for (int mi = 0; mi < 4; mi++) {
            int o = (wm*64 + mi*16 + lm)*LSTR + quad*8;
            ah[mi] = *(const bf16x8*)&sm[o];
            al[mi] = *(const bf16x8*)&sm[LREG + o];
        }
        #pragma unroll
        for (int ni = 0; ni < 4; ni++) {
            int o = (wn*64 + ni*16 + lm)*LSTR + quad*8;
            bh[ni] = *(const bf16x8*)&sm[2*LREG + o];
            bl[ni] = *(const bf16x8*)&sm[3*LREG + o];
        }
        #pragma unroll
        for (int mi = 0; mi < 4; mi++)
            #pragma unroll
            for (int ni = 0; ni < 4; ni++) {
                acc[mi][ni] = __builtin_amdgcn_mfma_f32_16x16x32_bf16(ah[mi], bh[ni], acc[mi][ni], 0, 0, 0);
                acc[mi][ni] = __builtin_amdgcn_mfma_f32_16x16x32_bf16(ah[mi], bl[ni], acc[mi][ni], 0, 0, 0);
                acc[mi][ni] = __builtin_amdgcn_mfma_f32_16x16x32_bf16(al[mi], bh[ni], acc[mi][ni], 0, 0, 0);
            }
        __syncthreads();
    }

    int f = *dflag;
    float s3[3] = {0,0,0}, q3[3] = {0,0,0};
    #pragma unroll
    for (int mi = 0; mi < 4; mi++) {
        int hor = ho0 + wm*64 + mi*16 + quad*4;
        float bv[4];
        #pragma unroll
        for (int r = 0; r < 4; r++) {
            int h = hor + r; if (h >= HO) h = HO - 1;
            bv[r] = ldf(bias, boff + h, f);
        }
        #pragma unroll
        for (int ni = 0; ni < 4; ni++) {
            int nc = n0 + wn*64 + ni*16 + lm;
            if (nc >= NN) continue;
            if constexpr (REGT) {
                if (hor <= 32) {              // rows hor..hor+3 all < 36
                    int c = hor / 12;
                    float4 v4;
                    v4.x = acc[mi][ni][0] + bv[0];
                    v4.y = acc[mi][ni][1] + bv[1];
                    v4.z = acc[mi][ni][2] + bv[2];
                    v4.w = acc[mi][ni][3] + bv[3];
                    *(float4*)(regT + ((size_t)(b0 + bz)*NN + nc)*36 + hor) = v4;
                    s3[c] += v4.x + v4.y + v4.z + v4.w;
                    q3[c] += v4.x*v4.x + v4.y*v4.y + v4.z*v4.z + v4.w*v4.w;
                }
            } else {
                size_t o = xb0 + (size_t)nc*HH + hor;
                float vals[4];
                #pragma unroll
                for (int r = 0; r < 4; r++) vals[r] = acc[mi][ni][r] + bv[r];
                if constexpr (RESID) {
                    BF4 rh = *(const BF4*)(Yhi + o);
                    BF4 rl = *(const BF4*)(Ylo + o);
                    vals[0] += bf2f(rh.a) + bf2f(rl.a);
                    vals[1] += bf2f(rh.b) + bf2f(rl.b);
                    vals[2] += bf2f(rh.c) + bf2f(rl.c);
                    vals[3] += bf2f(rh.d) + bf2f(rl.d);
                }
                if constexpr (RELU) {
                    #pragma unroll
                    for (int r = 0; r < 4; r++) vals[r] = fmaxf(vals[r], 0.f);
                }
                BF4 hi, lo;
                hi.a = __float2bfloat16(vals[0]); lo.a = __float2bfloat16(vals[0] - bf2f(hi.a));
                hi.b = __float2bfloat16(vals[1]); lo.b = __float2bfloat16(vals[1] - bf2f(hi.b));
                hi.c = __float2bfloat16(vals[2]); lo.c = __float2bfloat16(vals[2] - bf2f(hi.c));
                hi.d = __float2bfloat16(vals[3]); lo.d = __float2bfloat16(vals[3] - bf2f(hi.d));
                *(BF4*)(Yhi + o) = hi;
                *(BF4*)(Ylo + o) = lo;
            }
        }
    }
    if constexpr (REGT) {
        // block-reduce 6 stat values in the (now free) staging LDS, one atomic each
        float* red = (float*)sm;     // 16384 floats available >= 6*256
        #pragma unroll
        for (int j = 0; j < 3; j++) { red[j*256 + tid] = s3[j]; red[(3+j)*256 + tid] = q3[j]; }
        __syncthreads();
        for (int st = 128; st > 0; st >>= 1) {
            if (tid < st) {
                #pragma unroll
                for (int j = 0; j < 6; j++) red[j*256 + tid] += red[j*256 + tid + st];
            }
            __syncthreads();
        }
        if (tid < 6) atomicAdd(&st2[tid], red[tid*256]);
    }
}

// ---------------- xpre = bn2(regT) + conv(bn1(in)); bn3 stats ----------------
__global__ void k_xpre_r11(const float* __restrict__ regT, const void* __restrict__ in,
                           const void* __restrict__ convW, const void* __restrict__ convb,
                           const int* __restrict__ dflag, const float* __restrict__ st1,
                           const float* __restrict__ st2, float* __restrict__ st3,
                           float* __restrict__ xpre)
{
    int f = *dflag;
    int i = blockIdx.x*256 + threadIdx.x;
    float s[3] = {0,0,0}, q[3] = {0,0,0};
    if (i < TOT_X) {
        int b = i / 31788, r1 = i % 31788;
        int c = r1 / NL, r2 = r1 % NL;
        int n = r2 / 12, l = r2 % 12;
        float m2 = st2[c] * (1.0f/CNT_PER_C);
        float v2 = st2[3+c] * (1.0f/CNT_PER_C) - m2*m2;
        float hidv = (regT[((size_t)b*NN + n)*36 + c*12 + l] - m2) / sqrtf(v2 + 1e-5f);
        float cx = ldf(convb, c, f);
        #pragma unroll
        for (int cc = 0; cc < 3; cc++) {
            float m1 = st1[cc] * (1.0f/CNT_PER_C);
            float v1 = st1[3+cc] * (1.0f/CNT_PER_C) - m1*m1;
            float xbv = (ldf(in, ((long)(b*3 + cc)*NN + n)*12 + l, f) - m1) / sqrtf(v1 + 1e-5f);
            cx += ldf(convW, c*3 + cc, f) * xbv;
        }
        float v = hidv + cx;
        xpre[i] = v;
        s[c] = v; q[c] = v*v;
    }
    __shared__ float red[6][256];
    int t = threadIdx.x;
    #pragma unroll
    for (int j = 0; j < 3; j++) { red[j][t] = s[j]; red[3+j][t] = q[j]; }
    __syncthreads();
    for (int st_ = 128; st_ > 0; st_ >>= 1) {
        if (t < st_) {
            #pragma unroll
            for (int j = 0; j < 6; j++) red[j][t] += red[j][t+st_];
        }
        __syncthreads();
    }
    if (t < 6) atomicAdd(&st3[t], red[t][0]);
}

// ---------------- tail per (b,n) ----------------
__global__ void __launch_bounds__(64)
k_tail_r11(const float* __restrict__ xpre, const float* __restrict__ st3,
           const float* __restrict__ phi, const float* __restrict__ topval,
           const int* __restrict__ topidx, const float* __restrict__ wc,
           const void* __restrict__ wie, const void* __restrict__ mixp,
           const int* __restrict__ dflag, float* __restrict__ out)
{
    int f = *dflag;
    int n = blockIdx.x, b = blockIdx.y, t = threadIdx.x;
    __shared__ float xe[3][10][12], mn[3][10], phis[24], ws[10];
    __shared__ float pm[3][10][12], pred[3][12];
    float m3[3], rs3[3];
    #pragma unroll
    for (int c = 0; c < 3; c++) {
        float m = st3[c] * (1.0f/CNT_PER_C);
        float v = st3[3+c] * (1.0f/CNT_PER_C) - m*m;
        m3[c] = m; rs3[c] = 1.0f / sqrtf(v + 1e-5f);
    }
    if (t < 24) phis[t] = phi[b*24 + t];
    if (t < 10) ws[t] = (t == 0 ? 1.0f : topval[n*9 + t - 1]) * ldf(wie, t, f);
    for (int i = t; i < 360; i += 64) {
        int c = i / 120, m = (i / 12) % 10, l = i % 12;
        int nn2 = (m == 0) ? n : topidx[n*9 + m - 1];
        xe[c][m][l] = (xpre[((size_t)(b*3 + c)*NN + nn2)*12 + l] - m3[c]) * rs3[c];
    }
    __syncthreads();
    if (t < 30) {
        int c = t / 10, m = t % 10;
        float s = 0.f;
        #pragma unroll
        for (int l = 0; l < 12; l++) s += xe[c][m][l];
        mn[c][m] = s * (1.0f/12.0f);
    }
    __syncthreads();
    float mix = ldf(mixp, 0, f);
    for (int pr = t; pr < 120; pr += 64) {
        int m = pr / 12, p = pr % 12;
        float y[3], sc[12], mx = -3.4e38f;
        #pragma unroll
        for (int c = 0; c < 3; c++) y[c] = phis[12+p] + mix*mn[c][m];
        #pragma unroll
        for (int l = 0; l < 12; l++) {
            float v = 0.f;
            #pragma unroll
            for (int c = 0; c < 3; c++) v += y[c] * (phis[l] + mix*mn[c][m]);
            sc[l] = v * (1.0f/36.0f); mx = fmaxf(mx, sc[l]);
        }
        float den = 0.f;
        #pragma unroll
        for (int l = 0; l < 12; l++) { float e = expf(sc[l] - mx); sc[l] = e; den += e; }
        float inv = 1.0f/den;
        float p0 = 0.f, p1 = 0.f, p2 = 0.f;
        #pragma unroll
        for (int l = 0; l < 12; l++) {
            float a = sc[l]*inv;
            p0 += a*xe[0][m][l]; p1 += a*xe[1][m][l]; p2 += a*xe[2][m][l];
        }
        pm[0][m][p] = p0; pm[1][m][p] = p1; pm[2][m][p] = p2;
    }
    __syncthreads();
    if (t < 36) {
        int c = t/12, p = t%12;
        float s = 0.f;
        #pragma unroll
        for (int m = 0; m < 10; m++) s += pm[c][m][p]*ws[m];
        pred[c][p] = s;
    }
    __syncthreads();
    if (t < 36) {
        int o = t/12, p = t%12;
        float o1 = wc[9+o]  + wc[o*3+0]*pred[0][p] + wc[o*3+1]*pred[1][p] + wc[o*3+2]*pred[2][p];
        float o2 = wc[21+o] + wc[12+o*3+0]*pred[0][p] + wc[12+o*3+1]*pred[1][p] + wc[12+o*3+2]*pred[2][p];
        out[((size_t)(b*3 + o)*NN + n)*12 + p] = o1 / (1.0f + expf(-o2));
    }
}

// ---------------------------------------------------------------------------
extern "C" void kernel_launch(void* const* d_in, const int* in_sizes, int n_in,
                              void* d_out, int out_size, void* d_ws, size_t ws_size,
                              hipStream_t stream)
{
    (void)in_sizes; (void)n_in;
    char* w = (char*)d_ws;
    auto alloc = [&](size_t bytes) { char* p = w; w += (bytes + 255) & ~(size_t)255; return p; };

    float* regT   = (float*)alloc((size_t)TOT_X*4);   // (b, N, 36)
    float* xpre   = (float*)alloc((size_t)TOT_X*4);
    __hip_bfloat16* Whi1 = (__hip_bfloat16*)alloc(786432*2);
    __hip_bfloat16* Wlo1 = (__hip_bfloat16*)alloc(786432*2);
    __hip_bfloat16* Whi2 = (__hip_bfloat16*)alloc(786432*2);
    __hip_bfloat16* Wlo2 = (__hip_bfloat16*)alloc(786432*2);
    __hip_bfloat16* rhi  = (__hip_bfloat16*)alloc(18432*2);
    __hip_bfloat16* rlo  = (__hip_bfloat16*)alloc(18432*2);
    float* e1     = (float*)alloc(113024*4);
    float* e2t    = (float*)alloc(113024*4);
    float* phi    = (float*)alloc(768*4);
    float* topval = (float*)alloc(7947*4);
    int*   topidx = (int*)alloc(7947*4);
    int*   tidx   = (int*)alloc(32*4);
    int*   didx   = (int*)alloc(32*4);
    float* stats  = (float*)alloc(18*4);  // bn1|bn2|bn3
    float* wc     = (float*)alloc(24*4);
    int*   dflag  = (int*)alloc(4);
    size_t fixedEnd = (size_t)(w - (char*)d_ws);

    const size_t XB = (size_t)NPAD*HH*2;
    int CH = 0;
    for (int c = 32; c >= 1; c >>= 1) {
        if (fixedEnd + 4*(size_t)c*XB + 4096 <= ws_size) { CH = c; break; }
    }
    if (CH == 0) {
        k_sent_r11<<<(out_size + 255)/256, 256, 0, stream>>>((float*)d_out, out_size);
        return;
    }
    char* regionB = w;
    __hip_bfloat16* Xahi = (__hip_bfloat16*)regionB;
    __hip_bfloat16* Xalo = (__hip_bfloat16*)(regionB + (size_t)CH*XB);
    __hip_bfloat16* Xbhi = (__hip_bfloat16*)(regionB + 2*(size_t)CH*XB);
    __hip_bfloat16* Xblo = (__hip_bfloat16*)(regionB + 3*(size_t)CH*XB);

    hipMemsetAsync(stats, 0, 18*4, stream);

    k_probe_r11<<<1, 256, 0, stream>>>((const unsigned short*)d_in[0], dflag);
    k_prep_r11<<<1, 256, 0, stream>>>(d_in[2], d_in[3], d_in[19], d_in[20], d_in[21], d_in[22],
                                      d_in[25], d_in[26], d_in[27], d_in[28], d_in[29], d_in[30],
                                      dflag, tidx, didx, phi, wc);
    k_wsplit_r11<<<1024, 256, 0, stream>>>(d_in[13], dflag, 786432, Whi1, Wlo1);
    k_wsplit_r11<<<1024, 256, 0, stream>>>(d_in[15], dflag, 786432, Whi2, Wlo2);
    k_wsplit_r11<<<72,   256, 0, stream>>>(d_in[17], dflag, 18432, rhi, rlo);

    k_e_r11<<<883, 256, 0, stream>>>(d_in[4], d_in[5], d_in[6], dflag, e1, e2t);
    k_graph_r11<<<883, 256, 0, stream>>>(e1, e2t, topval, topidx);
    k_bn1_r11<<<512, 256, 0, stream>>>(d_in[0], dflag, stats);

    for (int b0 = 0; b0 < BB; b0 += CH) {
        k_hid_r11<<<dim3(111, CH), 256, 0, stream>>>(d_in[0], d_in[4], d_in[7], d_in[8],
                                                     d_in[9], d_in[10], tidx, didx, dflag,
                                                     stats, b0, Xahi, Xalo);
        for (int i = 0; i < 3; i++) {
            k_gemm_r11<true, false, false><<<dim3(7, 4, CH), 256, 0, stream>>>(
                Whi1, Wlo1, (long)i*HH*HH, d_in[14], (long)i*HH, dflag,
                Xahi, Xalo, Xbhi, Xblo, (float*)nullptr, (float*)nullptr, HH, b0);
            k_gemm_r11<false, true, false><<<dim3(7, 4, CH), 256, 0, stream>>>(
                Whi2, Wlo2, (long)i*HH*HH, d_in[16], (long)i*HH, dflag,
                Xbhi, Xblo, Xahi, Xalo, (float*)nullptr, (float*)nullptr, HH, b0);
        }
        k_gemm_r11<false, false, true><<<dim3(7, 1, CH), 256, 0, stream>>>(
            rhi, rlo, 0, d_in[18], 0, dflag,
            Xahi, Xalo, (__hip_bfloat16*)nullptr, (__hip_bfloat16*)nullptr,
            regT, stats + 6, 36, b0);
    }

    k_xpre_r11<<<3974, 256, 0, stream>>>(regT, d_in[0], d_in[11], d_in[12], dflag,
                                         stats, stats + 6, stats + 12, xpre);
    k_tail_r11<<<dim3(NN, BB), 64, 0, stream>>>(xpre, stats + 12, phi, topval, topidx, wc,
                                                d_in[24], d_in[23], dflag, (float*)d_out);
}

// Round 12
// 838.027 us; speedup vs baseline: 101.6663x; 1.0964x over previous
//
#include <hip/hip_runtime.h>
#include <hip/hip_bf16.h>

// ---------------------------------------------------------------------------
// STD2Vformer forward, MI355X. Round 12 (R11 passed @919us):
//  - ALL same-address atomicAdd stat paths replaced by per-block partials +
//    tiny finalize kernels (theory: 24k serialized L2 RMWs = k_xpre's 92us)
//  - k_xpre: 1024-block grid-stride, hoisted bn constants (no per-elem sqrt)
//  - stats memset dropped; everything else identical to R11
// ---------------------------------------------------------------------------

#define NN 883
#define NPAD 896
#define BB 32
#define HH 512
#define NL 10596            // N*L
#define CNT_PER_C 339072.0f // B*N*L
#define TOT_X 1017216       // B*C*N*L
#define LSTR 32             // LDS row stride in shorts (64B) - global_load_lds layout
#define LREG 4096           // shorts per LDS operand region (128*LSTR)

typedef __attribute__((ext_vector_type(8))) short bf16x8;
typedef __attribute__((ext_vector_type(4))) float f32x4;

static __device__ __forceinline__ float bf2f(__hip_bfloat16 v) { return __bfloat162float(v); }
static __device__ __forceinline__ float ldf(const void* p, long i, int f) {
    return f ? ((const float*)p)[i] : bf2f(((const __hip_bfloat16*)p)[i]);
}
static __device__ __forceinline__ unsigned short bfbits(float v) {
    __hip_bfloat16 h = __float2bfloat16(v);
    return *(unsigned short*)&h;
}
static __device__ __forceinline__ void async_copy16(const void* g, void* l) {
    __builtin_amdgcn_global_load_lds((const __attribute__((address_space(1))) void*)g,
                                     (__attribute__((address_space(3))) void*)l, 16, 0, 0);
}

struct alignas(8) BF4 { __hip_bfloat16 a, b, c, d; };

// ---------------- sentinel ----------------
__global__ void k_sent_r12(float* __restrict__ out, int n)
{
    int i = blockIdx.x*256 + threadIdx.x;
    if (i < n) out[i] = 1000.0f;
}

// ---------------- input dtype probe ----------------
__global__ void k_probe_r12(const unsigned short* __restrict__ u, int* __restrict__ flag)
{
    int t = threadIdx.x, cnt = 0;
    for (int i = t; i < 4096; i += 256) {
        int e = (u[i] >> 7) & 0xFF;
        cnt += (e >= 0xC0);
    }
    __shared__ int r[256];
    r[t] = cnt; __syncthreads();
    for (int s = 128; s > 0; s >>= 1) { if (t < s) r[t] += r[t+s]; __syncthreads(); }
    if (t == 0) *flag = (r[0] > 8) ? 1 : 0;
}

// ---------------- finalize: sum P rows of 6 partials -> out[0..5] ----------------
__global__ void k_fin_r12(const float* __restrict__ pb, int P, float* __restrict__ out)
{
    int t = threadIdx.x;
    float s[6] = {0,0,0,0,0,0};
    for (int r = t; r < P; r += 256)
        #pragma unroll
        for (int j = 0; j < 6; j++) s[j] += pb[r*6 + j];
    __shared__ float red[6][256];
    #pragma unroll
    for (int j = 0; j < 6; j++) red[j][t] = s[j];
    __syncthreads();
    for (int st = 128; st > 0; st >>= 1) {
        if (t < st) {
            #pragma unroll
            for (int j = 0; j < 6; j++) red[j][t] += red[j][t+st];
        }
        __syncthreads();
    }
    if (t < 6) out[t] = red[t][0];
}

// ---------------- weight hi/lo split ----------------
__global__ void k_wsplit_r12(const void* __restrict__ src, const int* __restrict__ dflag,
                             int n, __hip_bfloat16* __restrict__ hi,
                             __hip_bfloat16* __restrict__ lo)
{
    int f = *dflag;
    for (int i = blockIdx.x*256 + threadIdx.x; i < n; i += gridDim.x*256) {
        float v = ldf(src, i, f);
        __hip_bfloat16 h = __float2bfloat16(v);
        hi[i] = h;
        lo[i] = __float2bfloat16(v - bf2f(h));
    }
}

// ---------------- prep: tidx, didx, phi(B,24), wc (combined GLU 3x3) ----------------
__global__ void k_prep_r12(const void* __restrict__ seqs, const void* __restrict__ tgts,
                           const void* __restrict__ w0, const void* __restrict__ b0,
                           const void* __restrict__ d2vW, const void* __restrict__ d2vb,
                           const void* __restrict__ fusW, const void* __restrict__ fusb,
                           const void* __restrict__ g1W, const void* __restrict__ g1b,
                           const void* __restrict__ g2W, const void* __restrict__ g2b,
                           const int* __restrict__ dflag,
                           int* __restrict__ tidx, int* __restrict__ didx,
                           float* __restrict__ phi, float* __restrict__ wc)
{
    int f = *dflag, t = threadIdx.x;
    if (t < 32) {
        int b = t;
        float h  = (ldf(seqs, (b*5+3)*12 + 11, f) + 0.5f) * 23.0f;
        float mi = (ldf(seqs, (b*5+4)*12 + 11, f) + 0.5f) * 59.0f;
        int ti = (int)((h * 60.0f + mi) / 5.0f);
        tidx[b] = ti < 0 ? 0 : (ti > 287 ? 287 : ti);
        int di = (int)((ldf(seqs, (b*5+2)*12 + 11, f) + 0.5f) * 6.0f);
        didx[b] = di < 0 ? 0 : (di > 6 ? 6 : di);
    }
    for (int i = t; i < 768; i += 256) {
        int b = i / 24, tt = i % 24;
        float tau[5];
        #pragma unroll
        for (int d = 0; d < 5; d++)
            tau[d] = (tt < 12) ? ldf(seqs, (b*5+d)*12 + tt, f)
                               : ldf(tgts, (b*5+d)*12 + tt - 12, f);
        float s = ldf(b0, 0, f);
        #pragma unroll
        for (int d = 0; d < 5; d++) s += tau[d] * ldf(w0, d, f);
        for (int k = 0; k < 16; k++) {
            float arg = ldf(d2vb, k, f);
            #pragma unroll
            for (int d = 0; d < 5; d++) arg += tau[d] * ldf(d2vW, k*5 + d, f);
            s += sinf(arg);
        }
        phi[i] = s;
    }
    if (t < 24) {
        if (t < 9) {
            int o = t / 3, c = t % 3; float s = 0.f;
            for (int d = 0; d < 128; d++) s += ldf(fusW, c*128+d, f) * ldf(g1W, d*3+o, f);
            wc[t] = s;
        } else if (t < 12) {
            int o = t - 9; float s = ldf(g1b, o, f);
            for (int d = 0; d < 128; d++) s += ldf(fusb, d, f) * ldf(g1W, d*3+o, f);
            wc[9 + o] = s;
        } else if (t < 21) {
            int j = t - 12; int o = j / 3, c = j % 3; float s = 0.f;
            for (int d = 0; d < 128; d++) s += ldf(fusW, c*128+d, f) * ldf(g2W, d*3+o, f);
            wc[12 + j] = s;
        } else {
            int o = t - 21; float s = ldf(g2b, o, f);
            for (int d = 0; d < 128; d++) s += ldf(fusb, d, f) * ldf(g2W, d*3+o, f);
            wc[21 + o] = s;
        }
    }
}

// ---------------- e1 (n-major) and e2t (d-major, transposed) ----------------
__global__ void k_e_r12(const void* __restrict__ mb, const void* __restrict__ We1,
                        const void* __restrict__ We2, const int* __restrict__ dflag,
                        float* __restrict__ e1, float* __restrict__ e2t)
{
    int f = *dflag;
    int idx = blockIdx.x*256 + threadIdx.x;       // 2*113024 exactly
    int which = idx >= 113024;
    int j = which ? idx - 113024 : idx;
    int d = j & 127, n = j >> 7;
    const void* W = which ? We2 : We1;
    float s = 0.f;
    for (int k = 0; k < 128; k++)
        s += ldf(mb, n*128 + k, f) * ldf(W, k*128 + d, f);
    if (which) e2t[d*NN + n] = s;
    else       e1[j] = s;
}

// ---- fused graph: row dot (coalesced e2t) + standardize + softmax + top9 ----
__global__ void __launch_bounds__(256)
k_graph_r12(const float* __restrict__ e1, const float* __restrict__ e2t,
            float* __restrict__ topval, int* __restrict__ topidx)
{
    int n = blockIdx.x, t = threadIdx.x;
    __shared__ float e1s[128];
    __shared__ float arow[NN];
    __shared__ float red[256];
    __shared__ int redi[256];
    if (t < 128) e1s[t] = e1[n*128 + t];
    __syncthreads();
    for (int m = t; m < NN; m += 256) {
        float acc = 0.f;
        #pragma unroll 8
        for (int k = 0; k < 128; k++) acc += e1s[k] * e2t[k*NN + m];
        arow[m] = acc;
    }
    __syncthreads();
    float s = 0.f;
    for (int m = t; m < NN; m += 256) s += arow[m];
    red[t] = s; __syncthreads();
    for (int st = 128; st > 0; st >>= 1) { if (t < st) red[t] += red[t+st]; __syncthreads(); }
    float mean = red[0] / 883.0f; __syncthreads();
    float ss = 0.f;
    for (int m = t; m < NN; m += 256) { float d = arow[m] - mean; ss += d*d; }
    red[t] = ss; __syncthreads();
    for (int st = 128; st > 0; st >>= 1) { if (t < st) red[t] += red[t+st]; __syncthreads(); }
    float rstd = 1.0f / sqrtf(red[0] / 882.0f); __syncthreads();
    for (int m = t; m < NN; m += 256) {
        float z = (arow[m] - mean) * rstd;
        z = fmaxf(z, 0.f);
        if (m == n) z -= 1e6f;
        arow[m] = z;
    }
    __syncthreads();
    float mx = -3.4e38f;
    for (int m = t; m < NN; m += 256) mx = fmaxf(mx, arow[m]);
    red[t] = mx; __syncthreads();
    for (int st = 128; st > 0; st >>= 1) { if (t < st) red[t] = fmaxf(red[t], red[t+st]); __syncthreads(); }
    float M = red[0]; __syncthreads();
    float ds = 0.f;
    for (int m = t; m < NN; m += 256) { float e = expf(arow[m] - M); arow[m] = e; ds += e; }
    red[t] = ds; __syncthreads();
    for (int st = 128; st > 0; st >>= 1) { if (t < st) red[t] += red[t+st]; __syncthreads(); }
    float inv = 1.0f / red[0]; __syncthreads();
    for (int m = t; m < NN; m += 256) arow[m] *= inv;
    __syncthreads();
    for (int j = 0; j < 9; j++) {
        float bv = -1.f; int bi = 0;
        for (int m = t; m < NN; m += 256) { float v = arow[m]; if (v > bv) { bv = v; bi = m; } }
        red[t] = bv; redi[t] = bi; __syncthreads();
        for (int st = 128; st > 0; st >>= 1) {
            if (t < st) {
                float ov = red[t+st]; int oi = redi[t+st];
                if (ov > red[t] || (ov == red[t] && oi < redi[t])) { red[t] = ov; redi[t] = oi; }
            }
            __syncthreads();
        }
        if (t == 0) {
            topval[n*9 + j] = red[0];
            topidx[n*9 + j] = redi[0];
            arow[redi[0]] = -1.f;
        }
        __syncthreads();
    }
}

// ---------------- bn1 stats -> per-block partials ----------------
__global__ void k_bn1_r12(const void* __restrict__ x, const int* __restrict__ dflag,
                          float* __restrict__ pb)
{
    int f = *dflag;
    float s[3] = {0,0,0}, q[3] = {0,0,0};
    for (int i = blockIdx.x*256 + threadIdx.x; i < TOT_X; i += 512*256) {
        int c = (i / NL) % 3;
        float v = ldf(x, i, f);
        s[c] += v; q[c] += v*v;
    }
    __shared__ float red[6][256];
    int t = threadIdx.x;
    #pragma unroll
    for (int j = 0; j < 3; j++) { red[j][t] = s[j]; red[3+j][t] = q[j]; }
    __syncthreads();
    for (int st_ = 128; st_ > 0; st_ >>= 1) {
        if (t < st_) {
            #pragma unroll
            for (int j = 0; j < 6; j++) red[j][t] += red[j][t+st_];
        }
        __syncthreads();
    }
    if (t < 6) pb[blockIdx.x*6 + t] = red[t][0];
}

// ---------------- build hidden (hi,lo); 8 nodes/block; bn1 inline ----------------
__global__ void __launch_bounds__(256)
k_hid_r12(const void* __restrict__ in, const void* __restrict__ mb,
          const void* __restrict__ tide, const void* __restrict__ diwe,
          const void* __restrict__ tsW, const void* __restrict__ tsb,
          const int* __restrict__ tidx, const int* __restrict__ didx,
          const int* __restrict__ dflag, const float* __restrict__ st1,
          int b0, __hip_bfloat16* __restrict__ Xhi, __hip_bfloat16* __restrict__ Xlo)
{
    int f = *dflag;
    int bl = blockIdx.y, bg = b0 + bl, t = threadIdx.x;
    int n0 = blockIdx.x * 8;
    __shared__ float tsw[128*37];
    __shared__ float tsbs[128];
    __shared__ float xbs[8][36];
    float m1[3], r1v[3];
    #pragma unroll
    for (int c = 0; c < 3; c++) {
        float m = st1[c] * (1.0f/CNT_PER_C);
        float v = st1[3+c] * (1.0f/CNT_PER_C) - m*m;
        m1[c] = m; r1v[c] = 1.0f / sqrtf(v + 1e-5f);
    }
    for (int i = t; i < 4608; i += 256)
        tsw[(i/36)*37 + (i%36)] = ldf(tsW, i, f);
    if (t < 128) tsbs[t] = ldf(tsb, t, f);
    for (int i = t; i < 288; i += 256) {
        int nl = i / 36, k = i % 36;
        int c = k / 12, l = k % 12;
        int n = n0 + nl; if (n >= NN) n = NN - 1;
        xbs[nl][k] = (ldf(in, ((long)(bg*3 + c)*NN + n)*12 + l, f) - m1[c]) * r1v[c];
    }
    __syncthreads();
    int nloc = t >> 5, lane = t & 31;
    int n = n0 + nloc;
    if (n >= NN) return;
    size_t base = ((size_t)bl*NPAD + n)*HH;
    const float* xr = xbs[nloc];
    #pragma unroll
    for (int j = 0; j < 8; j++) {
        int ch0 = j*64 + lane*2;
        float v0, v1;
        if (j < 2) {
            float a0 = tsbs[ch0], a1 = tsbs[ch0+1];
            #pragma unroll
            for (int k = 0; k < 36; k++) {
                float xv = xr[k];
                a0 += xv * tsw[ch0*37 + k];
                a1 += xv * tsw[(ch0+1)*37 + k];
            }
            v0 = a0; v1 = a1;
        } else if (j < 4) {
            v0 = ldf(mb, n*128 + ch0 - 128, f);
            v1 = ldf(mb, n*128 + ch0 - 127, f);
        } else if (j < 6) {
            v0 = ldf(tide, tidx[bg]*128 + ch0 - 256, f);
            v1 = ldf(tide, tidx[bg]*128 + ch0 - 255, f);
        } else {
            v0 = ldf(diwe, didx[bg]*128 + ch0 - 384, f);
            v1 = ldf(diwe, didx[bg]*128 + ch0 - 383, f);
        }
        unsigned short h0 = bfbits(v0), h1 = bfbits(v1);
        __hip_bfloat16 hb0, hb1;
        *(unsigned short*)&hb0 = h0; *(unsigned short*)&hb1 = h1;
        unsigned short l0 = bfbits(v0 - bf2f(hb0)), l1 = bfbits(v1 - bf2f(hb1));
        *(unsigned*)(Xhi + base + ch0) = (unsigned)h0 | ((unsigned)h1 << 16);
        *(unsigned*)(Xlo + base + ch0) = (unsigned)l0 | ((unsigned)l1 << 16);
    }
}

// ---------------- MFMA GEMM: async staging, hi/lo, 3 MFMAs/frag ----------------
// REGT mode: write regT (b,N,36) float4 + bn2 partials (per-block, NO atomics)
template<bool RELU, bool RESID, bool REGT>
__global__ void __launch_bounds__(256)
k_gemm_r12(const __hip_bfloat16* __restrict__ Whi, const __hip_bfloat16* __restrict__ Wlo,
           long Woff, const void* __restrict__ bias, long boff,
           const int* __restrict__ dflag,
           const __hip_bfloat16* __restrict__ Xhi, const __hip_bfloat16* __restrict__ Xlo,
           __hip_bfloat16* __restrict__ Yhi, __hip_bfloat16* __restrict__ Ylo,
           float* __restrict__ regT, float* __restrict__ pb2, int HO, int b0)
{
    __shared__ __align__(16) short sm[4*LREG];   // Ahi|Alo|Bhi|Blo (32 KB)
    int tid = threadIdx.x, bz = blockIdx.z;
    int n0 = blockIdx.x * 128, ho0 = blockIdx.y * 128;
    int lane = tid & 63, wave = tid >> 6;
    int wm = wave & 1, wn = wave >> 1;
    int lm = lane & 15, quad = lane >> 4;

    f32x4 acc[4][4];
    #pragma unroll
    for (int i = 0; i < 4; i++)
        #pragma unroll
        for (int j = 0; j < 4; j++) acc[i][j] = (f32x4){0.f, 0.f, 0.f, 0.f};

    const size_t xb0 = (size_t)bz*NPAD*HH;
    int rri[2], nBi[2], kci[2], lofsi[2];
    #pragma unroll
    for (int it = 0; it < 2; it++) {
        int s = it*256 + tid;
        int row = s >> 2; kci[it] = (s & 3) * 8;
        int rr = ho0 + row; rri[it] = (rr >= HO) ? HO - 1 : rr;
        int nB = n0 + row; nBi[it] = (nB >= NN) ? NN - 1 : nB;
        lofsi[it] = s * 8;
    }

    for (int k0 = 0; k0 < 512; k0 += 32) {
        #pragma unroll
        for (int it = 0; it < 2; it++) {
            size_t wofs = (size_t)Woff + (size_t)rri[it]*512 + k0 + kci[it];
            size_t xofs = xb0 + (size_t)nBi[it]*HH + k0 + kci[it];
            int lofs = lofsi[it];
            async_copy16(Whi + wofs, &sm[lofs]);
            async_copy16(Wlo + wofs, &sm[LREG + lofs]);
            async_copy16(Xhi + xofs, &sm[2*LREG + lofs]);
            async_copy16(Xlo + xofs, &sm[3*LREG + lofs]);
        }
        __syncthreads();
        bf16x8 ah[4], al[4], bh[4], bl[4];
        #pragma unroll
        for (int mi = 0; mi < 4; mi++) {
            int o = (wm*64 + mi*16 + lm)*LSTR + quad*8;
            ah[mi] = *(const bf16x8*)&sm[o];
            al[mi] = *(const bf16x8*)&sm[LREG + o];
        }
        #pragma unroll
        for (int ni = 0; ni < 4; ni++) {
            int o = (wn*64 + ni*16 + lm)*LSTR + quad*8;
            bh[ni] = *(const bf16x8*)&sm[2*LREG + o];
            bl[ni] = *(const bf16x8*)&sm[3*LREG + o];
        }
        #pragma unroll
        for (int mi = 0; mi < 4; mi++)
            #pragma unroll
            for (int ni = 0; ni < 4; ni++) {
                acc[mi][ni] = __builtin_amdgcn_mfma_f32_16x16x32_bf16(ah[mi], bh[ni], acc[mi][ni], 0, 0, 0);
                acc[mi][ni] = __builtin_amdgcn_mfma_f32_16x16x32_bf16(ah[mi], bl[ni], acc[mi][ni], 0, 0, 0);
                acc[mi][ni] = __builtin_amdgcn_mfma_f32_16x16x32_bf16(al[mi], bh[ni], acc[mi][ni], 0, 0, 0);
            }
        __syncthreads();
    }

    int f = *dflag;
    float s3[3] = {0,0,0}, q3[3] = {0,0,0};
    #pragma unroll
    for (int mi = 0; mi < 4; mi++) {
        int hor = ho0 + wm*64 + mi*16 + quad*4;
        float bv[4];
        #pragma unroll
        for (int r = 0; r < 4; r++) {
            int h = hor + r; if (h >= HO) h = HO - 1;
            bv[r] = ldf(bias, boff + h, f);
        }
        #pragma unroll
        for (int ni = 0; ni < 4; ni++) {
            int nc = n0 + wn*64 + ni*16 + lm;
            if (nc >= NN) continue;
            if constexpr (REGT) {
                if (hor <= 32) {
                    int c = hor / 12;
                    float4 v4;
                    v4.x = acc[mi][ni][0] + bv[0];
                    v4.y = acc[mi][ni][1] + bv[1];
                    v4.z = acc[mi][ni][2] + bv[2];
                    v4.w = acc[mi][ni][3] + bv[3];
                    *(float4*)(regT + ((size_t)(b0 + bz)*NN + nc)*36 + hor) = v4;
                    s3[c] += v4.x + v4.y + v4.z + v4.w;
                    q3[c] += v4.x*v4.x + v4.y*v4.y + v4.z*v4.z + v4.w*v4.w;
                }
            } else {
                size_t o = xb0 + (size_t)nc*HH + hor;
                float vals[4];
                #pragma unroll
                for (int r = 0; r < 4; r++) vals[r] = acc[mi][ni][r] + bv[r];
                if constexpr (RESID) {
                    BF4 rh = *(const BF4*)(Yhi + o);
                    BF4 rl = *(const BF4*)(Ylo + o);
                    vals[0] += bf2f(rh.a) + bf2f(rl.a);
                    vals[1] += bf2f(rh.b) + bf2f(rl.b);
                    vals[2] += bf2f(rh.c) + bf2f(rl.c);
                    vals[3] += bf2f(rh.d) + bf2f(rl.d);
                }
                if constexpr (RELU) {
                    #pragma unroll
                    for (int r = 0; r < 4; r++) vals[r] = fmaxf(vals[r], 0.f);
                }
                BF4 hi, lo;
                hi.a = __float2bfloat16(vals[0]); lo.a = __float2bfloat16(vals[0] - bf2f(hi.a));
                hi.b = __float2bfloat16(vals[1]); lo.b = __float2bfloat16(vals[1] - bf2f(hi.b));
                hi.c = __float2bfloat16(vals[2]); lo.c = __float2bfloat16(vals[2] - bf2f(hi.c));
                hi.d = __float2bfloat16(vals[3]); lo.d = __float2bfloat16(vals[3] - bf2f(hi.d));
                *(BF4*)(Yhi + o) = hi;
                *(BF4*)(Ylo + o) = lo;
            }
        }
    }
    if constexpr (REGT) {
        float* red = (float*)sm;
        #pragma unroll
        for (int j = 0; j < 3; j++) { red[j*256 + tid] = s3[j]; red[(3+j)*256 + tid] = q3[j]; }
        __syncthreads();
        for (int st = 128; st > 0; st >>= 1) {
            if (tid < st) {
                #pragma unroll
                for (int j = 0; j < 6; j++) red[j*256 + tid] += red[j*256 + tid + st];
            }
            __syncthreads();
        }
        if (tid < 6) pb2[((b0 + bz)*7 + blockIdx.x)*6 + tid] = red[tid*256];
    }
}

// ---------------- xpre = bn2(regT) + conv(bn1(in)); bn3 partials ----------------
__global__ void __launch_bounds__(256)
k_xpre_r12(const float* __restrict__ regT, const void* __restrict__ in,
           const void* __restrict__ convW, const void* __restrict__ convb,
           const int* __restrict__ dflag, const float* __restrict__ st1,
           const float* __restrict__ st2, float* __restrict__ pb3,
           float* __restrict__ xpre)
{
    int f = *dflag;
    float m1[3], r1[3], m2[3], r2[3], cw[9], cb[3];
    #pragma unroll
    for (int c = 0; c < 3; c++) {
        float m = st1[c] * (1.0f/CNT_PER_C);
        float v = st1[3+c] * (1.0f/CNT_PER_C) - m*m;
        m1[c] = m; r1[c] = 1.0f / sqrtf(v + 1e-5f);
        float mm = st2[c] * (1.0f/CNT_PER_C);
        float vv = st2[3+c] * (1.0f/CNT_PER_C) - mm*mm;
        m2[c] = mm; r2[c] = 1.0f / sqrtf(vv + 1e-5f);
        cb[c] = ldf(convb, c, f);
    }
    #pragma unroll
    for (int j = 0; j < 9; j++) cw[j] = ldf(convW, j, f);
    float s0=0,s1=0,s2=0,q0=0,q1=0,q2=0;
    for (int i = blockIdx.x*256 + threadIdx.x; i < TOT_X; i += 1024*256) {
        int b = i / 31788, r1_ = i % 31788;
        int c = r1_ / NL, r2_ = r1_ % NL;
        int n = r2_ / 12, l = r2_ % 12;
        float hidv = (regT[((size_t)b*NN + n)*36 + c*12 + l] - m2[c]) * r2[c];
        float cx = cb[c];
        #pragma unroll
        for (int cc = 0; cc < 3; cc++) {
            float xbv = (ldf(in, ((long)(b*3 + cc)*NN + n)*12 + l, f) - m1[cc]) * r1[cc];
            cx += cw[c*3 + cc] * xbv;
        }
        float v = hidv + cx;
        xpre[i] = v;
        float v2 = v*v;
        s0 += (c == 0) ? v : 0.f;  q0 += (c == 0) ? v2 : 0.f;
        s1 += (c == 1) ? v : 0.f;  q1 += (c == 1) ? v2 : 0.f;
        s2 += (c == 2) ? v : 0.f;  q2 += (c == 2) ? v2 : 0.f;
    }
    __shared__ float red[6][256];
    int t = threadIdx.x;
    red[0][t] = s0; red[1][t] = s1; red[2][t] = s2;
    red[3][t] = q0; red[4][t] = q1; red[5][t] = q2;
    __syncthreads();
    for (int st_ = 128; st_ > 0; st_ >>= 1) {
        if (t < st_) {
            #pragma unroll
            for (int j = 0; j < 6; j++) red[j][t] += red[j][t+st_];
        }
        __syncthreads();
    }
    if (t < 6) pb3[blockIdx.x*6 + t] = red[t][0];
}

// ---------------- tail per (b,n) ----------------
__global__ void __launch_bounds__(64)
k_tail_r12(const float* __restrict__ xpre, const float* __restrict__ st3,
           const float* __restrict__ phi, const float* __restrict__ topval,
           const int* __restrict__ topidx, const float* __restrict__ wc,
           const void* __restrict__ wie, const void* __restrict__ mixp,
           const int* __restrict__ dflag, float* __restrict__ out)
{
    int f = *dflag;
    int n = blockIdx.x, b = blockIdx.y, t = threadIdx.x;
    __shared__ float xe[3][10][12], mn[3][10], phis[24], ws[10];
    __shared__ float pm[3][10][12], pred[3][12];
    float m3[3], rs3[3];
    #pragma unroll
    for (int c = 0; c < 3; c++) {
        float m = st3[c] * (1.0f/CNT_PER_C);
        float v = st3[3+c] * (1.0f/CNT_PER_C) - m*m;
        m3[c] = m; rs3[c] = 1.0f / sqrtf(v + 1e-5f);
    }
    if (t < 24) phis[t] = phi[b*24 + t];
    if (t < 10) ws[t] = (t == 0 ? 1.0f : topval[n*9 + t - 1]) * ldf(wie, t, f);
    for (int i = t; i < 360; i += 64) {
        int c = i / 120, m = (i / 12) % 10, l = i % 12;
        int nn2 = (m == 0) ? n : topidx[n*9 + m - 1];
        xe[c][m][l] = (xpre[((size_t)(b*3 + c)*NN + nn2)*12 + l] - m3[c]) * rs3[c];
    }
    __syncthreads();
    if (t < 30) {
        int c = t / 10, m = t % 10;
        float s = 0.f;
        #pragma unroll
        for (int l = 0; l < 12; l++) s += xe[c][m][l];
        mn[c][m] = s * (1.0f/12.0f);
    }
    __syncthreads();
    float mix = ldf(mixp, 0, f);
    for (int pr = t; pr < 120; pr += 64) {
        int m = pr / 12, p = pr % 12;
        float y[3], sc[12], mx = -3.4e38f;
        #pragma unroll
        for (int c = 0; c < 3; c++) y[c] = phis[12+p] + mix*mn[c][m];
        #pragma unroll
        for (int l = 0; l < 12; l++) {
            float v = 0.f;
            #pragma unroll
            for (int c = 0; c < 3; c++) v += y[c] * (phis[l] + mix*mn[c][m]);
            sc[l] = v * (1.0f/36.0f); mx = fmaxf(mx, sc[l]);
        }
        float den = 0.f;
        #pragma unroll
        for (int l = 0; l < 12; l++) { float e = expf(sc[l] - mx); sc[l] = e; den += e; }
        float inv = 1.0f/den;
        float p0 = 0.f, p1 = 0.f, p2 = 0.f;
        #pragma unroll
        for (int l = 0; l < 12; l++) {
            float a = sc[l]*inv;
            p0 += a*xe[0][m][l]; p1 += a*xe[1][m][l]; p2 += a*xe[2][m][l];
        }
        pm[0][m][p] = p0; pm[1][m][p] = p1; pm[2][m][p] = p2;
    }
    __syncthreads();
    if (t < 36) {
        int c = t/12, p = t%12;
        float s = 0.f;
        #pragma unroll
        for (int m = 0; m < 10; m++) s += pm[c][m][p]*ws[m];
        pred[c][p] = s;
    }
    __syncthreads();
    if (t < 36) {
        int o = t/12, p = t%12;
        float o1 = wc[9+o]  + wc[o*3+0]*pred[0][p] + wc[o*3+1]*pred[1][p] + wc[o*3+2]*pred[2][p];
        float o2 = wc[21+o] + wc[12+o*3+0]*pred[0][p] + wc[12+o*3+1]*pred[1][p] + wc[12+o*3+2]*pred[2][p];
        out[((size_t)(b*3 + o)*NN + n)*12 + p] = o1 / (1.0f + expf(-o2));
    }
}

// ---------------------------------------------------------------------------
extern "C" void kernel_launch(void* const* d_in, const int* in_sizes, int n_in,
                              void* d_out, int out_size, void* d_ws, size_t ws_size,
                              hipStream_t stream)
{
    (void)in_sizes; (void)n_in;
    char* w = (char*)d_ws;
    auto alloc = [&](size_t bytes) { char* p = w; w += (bytes + 255) & ~(size_t)255; return p; };

    float* regT   = (float*)alloc((size_t)TOT_X*4);   // (b, N, 36)
    float* xpre   = (float*)alloc((size_t)TOT_X*4);
    __hip_bfloat16* Whi1 = (__hip_bfloat16*)alloc(786432*2);
    __hip_bfloat16* Wlo1 = (__hip_bfloat16*)alloc(786432*2);
    __hip_bfloat16* Whi2 = (__hip_bfloat16*)alloc(786432*2);
    __hip_bfloat16* Wlo2 = (__hip_bfloat16*)alloc(786432*2);
    __hip_bfloat16* rhi  = (__hip_bfloat16*)alloc(18432*2);
    __hip_bfloat16* rlo  = (__hip_bfloat16*)alloc(18432*2);
    float* e1     = (float*)alloc(113024*4);
    float* e2t    = (float*)alloc(113024*4);
    float* phi    = (float*)alloc(768*4);
    float* topval = (float*)alloc(7947*4);
    int*   topidx = (int*)alloc(7947*4);
    int*   tidx   = (int*)alloc(32*4);
    int*   didx   = (int*)alloc(32*4);
    float* stats  = (float*)alloc(18*4);  // bn1|bn2|bn3 (written by k_fin)
    float* wc     = (float*)alloc(24*4);
    int*   dflag  = (int*)alloc(4);
    float* pb1    = (float*)alloc(512*6*4);
    float* pb2    = (float*)alloc(224*6*4);
    float* pb3    = (float*)alloc(1024*6*4);
    size_t fixedEnd = (size_t)(w - (char*)d_ws);

    const size_t XB = (size_t)NPAD*HH*2;
    int CH = 0;
    for (int c = 32; c >= 1; c >>= 1) {
        if (fixedEnd + 4*(size_t)c*XB + 4096 <= ws_size) { CH = c; break; }
    }
    if (CH == 0) {
        k_sent_r12<<<(out_size + 255)/256, 256, 0, stream>>>((float*)d_out, out_size);
        return;
    }
    char* regionB = w;
    __hip_bfloat16* Xahi = (__hip_bfloat16*)regionB;
    __hip_bfloat16* Xalo = (__hip_bfloat16*)(regionB + (size_t)CH*XB);
    __hip_bfloat16* Xbhi = (__hip_bfloat16*)(regionB + 2*(size_t)CH*XB);
    __hip_bfloat16* Xblo = (__hip_bfloat16*)(regionB + 3*(size_t)CH*XB);

    k_probe_r12<<<1, 256, 0, stream>>>((const unsigned short*)d_in[0], dflag);
    k_prep_r12<<<1, 256, 0, stream>>>(d_in[2], d_in[3], d_in[19], d_in[20], d_in[21], d_in[22],
                                      d_in[25], d_in[26], d_in[27], d_in[28], d_in[29], d_in[30],
                                      dflag, tidx, didx, phi, wc);
    k_wsplit_r12<<<1024, 256, 0, stream>>>(d_in[13], dflag, 786432, Whi1, Wlo1);
    k_wsplit_r12<<<1024, 256, 0, stream>>>(d_in[15], dflag, 786432, Whi2, Wlo2);
    k_wsplit_r12<<<72,   256, 0, stream>>>(d_in[17], dflag, 18432, rhi, rlo);

    k_e_r12<<<883, 256, 0, stream>>>(d_in[4], d_in[5], d_in[6], dflag, e1, e2t);
    k_graph_r12<<<883, 256, 0, stream>>>(e1, e2t, topval, topidx);
    k_bn1_r12<<<512, 256, 0, stream>>>(d_in[0], dflag, pb1);
    k_fin_r12<<<1, 256, 0, stream>>>(pb1, 512, stats);

    for (int b0 = 0; b0 < BB; b0 += CH) {
        k_hid_r12<<<dim3(111, CH), 256, 0, stream>>>(d_in[0], d_in[4], d_in[7], d_in[8],
                                                     d_in[9], d_in[10], tidx, didx, dflag,
                                                     stats, b0, Xahi, Xalo);
        for (int i = 0; i < 3; i++) {
            k_gemm_r12<true, false, false><<<dim3(7, 4, CH), 256, 0, stream>>>(
                Whi1, Wlo1, (long)i*HH*HH, d_in[14], (long)i*HH, dflag,
                Xahi, Xalo, Xbhi, Xblo, (float*)nullptr, (float*)nullptr, HH, b0);
            k_gemm_r12<false, true, false><<<dim3(7, 4, CH), 256, 0, stream>>>(
                Whi2, Wlo2, (long)i*HH*HH, d_in[16], (long)i*HH, dflag,
                Xbhi, Xblo, Xahi, Xalo, (float*)nullptr, (float*)nullptr, HH, b0);
        }
        k_gemm_r12<false, false, true><<<dim3(7, 1, CH), 256, 0, stream>>>(
            rhi, rlo, 0, d_in[18], 0, dflag,
            Xahi, Xalo, (__hip_bfloat16*)nullptr, (__hip_bfloat16*)nullptr,
            regT, pb2, 36, b0);
    }
    k_fin_r12<<<1, 256, 0, stream>>>(pb2, 224, stats + 6);

    k_xpre_r12<<<1024, 256, 0, stream>>>(regT, d_in[0], d_in[11], d_in[12], dflag,
                                         stats, stats + 6, pb3, xpre);
    k_fin_r12<<<1, 256, 0, stream>>>(pb3, 1024, stats + 12);

    k_tail_r12<<<dim3(NN, BB), 64, 0, stream>>>(xpre, stats + 12, phi, topval, topidx, wc,
                                                d_in[24], d_in[23], dflag, (float*)d_out);
}